// Round 8
// baseline (1767.435 us; speedup 1.0000x reference)
//
#include <hip/hip_runtime.h>
#include <math.h>

#define NN 40000
#define EE 640000
#define DD 128
#define EDD 16
#define LL 3
#define NPB 16   // nodes per block in edge_msg_kernel

__device__ __constant__ float kBnInv = 0.9999950000374997f; // 1/sqrt(1+1e-5)

typedef __bf16 bf16x8 __attribute__((ext_vector_type(8)));
typedef float  f32x4  __attribute__((ext_vector_type(4)));

// pack two floats to bf16 pair (RTNE) in one uint: lo16=a, hi16=b
__device__ __forceinline__ unsigned pack_bf2(float a, float b) {
    unsigned ua = __float_as_uint(a), ub = __float_as_uint(b);
    ua = (ua + 0x7fffu + ((ua >> 16) & 1u)) >> 16;
    ub = (ub + 0x7fffu + ((ub >> 16) & 1u)) & 0xffff0000u;
    return ua | ub;
}
__device__ __forceinline__ unsigned short bf16r(float x) {
    unsigned u = __float_as_uint(x);
    u = (u + 0x7fffu + ((u >> 16) & 1u)) >> 16;
    return (unsigned short)u;
}

// ---------------------------------------------------------------------------
// h = x @ node_W + node_b; also emits packed-bf16 hb
__global__ __launch_bounds__(256) void node_enc_kernel(
    const float* __restrict__ x, const float* __restrict__ W,
    const float* __restrict__ b, float* __restrict__ h,
    unsigned* __restrict__ hb)
{
    __shared__ float xs[32][DD];
    const int t = threadIdx.x;
    const long rowbase = (long)blockIdx.x * 32;

    const float4* x4 = (const float4*)(x + rowbase * DD);
    float4* xs4 = (float4*)&xs[0][0];
#pragma unroll
    for (int i = 0; i < 4; i++) xs4[t + i * 256] = x4[t + i * 256];
    __syncthreads();

    const int c  = (t & 31) * 4;
    const int r0 = (t >> 5) * 4;

    float acc[4][4] = {};
    for (int k4 = 0; k4 < DD; k4 += 4) {
        float4 xr[4];
#pragma unroll
        for (int i = 0; i < 4; i++) xr[i] = *(const float4*)&xs[r0 + i][k4];
#pragma unroll
        for (int kk = 0; kk < 4; kk++) {
            const float4 w = *(const float4*)(W + (k4 + kk) * DD + c);
#pragma unroll
            for (int i = 0; i < 4; i++) {
                const float xv = ((const float*)&xr[i])[kk];
                acc[i][0] = fmaf(xv, w.x, acc[i][0]);
                acc[i][1] = fmaf(xv, w.y, acc[i][1]);
                acc[i][2] = fmaf(xv, w.z, acc[i][2]);
                acc[i][3] = fmaf(xv, w.w, acc[i][3]);
            }
        }
    }
    const float4 bv = *(const float4*)(b + c);
#pragma unroll
    for (int i = 0; i < 4; i++) {
        const long row = rowbase + r0 + i;
        float4 ov = { acc[i][0] + bv.x, acc[i][1] + bv.y,
                      acc[i][2] + bv.z, acc[i][3] + bv.w };
        *(float4*)(h + row * DD + c) = ov;
        uint2 pv = { pack_bf2(ov.x, ov.y), pack_bf2(ov.z, ov.w) };
        *(uint2*)(hb + row * 64 + (c >> 1)) = pv;
    }
}

// ---------------------------------------------------------------------------
// weight transpose + bf16 cast
__global__ __launch_bounds__(256) void wcast_kernel(
    const float* __restrict__ W1, const float* __restrict__ W2,
    unsigned short* __restrict__ w1t, unsigned short* __restrict__ w2t)
{
    const int idx = blockIdx.x * 256 + threadIdx.x;   // grid covers LL*32768
    const int l = idx >> 15, r = idx & 32767;
    {   const int n = r >> 7, k = r & 127;
        w1t[idx] = bf16r(W1[(l << 15) + (k << 8) + n]);
    }
    {   const int n = r >> 8, k = r & 255;
        w2t[idx] = bf16r(W2[(l << 15) + (k << 7) + n]);
    }
}

// ---------------------------------------------------------------------------
// CSR build
__global__ __launch_bounds__(256) void hist_kernel(
    const int* __restrict__ edge_index, int* __restrict__ counts)
{
    const int i = blockIdx.x * 256 + threadIdx.x;
    atomicAdd(&counts[edge_index[EE + i]], 1);
}

__global__ __launch_bounds__(256) void scan1_kernel(
    const int* __restrict__ counts, int* __restrict__ scanned,
    int* __restrict__ partials)
{
    __shared__ int sdata[256];
    const int t = threadIdx.x;
    const int base = blockIdx.x * 1024 + t * 4;
    int v[4]; int sum = 0;
#pragma unroll
    for (int i = 0; i < 4; i++) {
        const int idx = base + i;
        v[i] = (idx < NN) ? counts[idx] : 0;
        sum += v[i];
    }
    sdata[t] = sum;
    __syncthreads();
    for (int off = 1; off < 256; off <<= 1) {
        int x = (t >= off) ? sdata[t - off] : 0;
        __syncthreads();
        sdata[t] += x;
        __syncthreads();
    }
    int run = sdata[t] - sum;
#pragma unroll
    for (int i = 0; i < 4; i++) {
        const int idx = base + i;
        if (idx < NN) scanned[idx] = run;
        run += v[i];
    }
    if (t == 255) partials[blockIdx.x] = sdata[255];
}

__global__ void scan2_kernel(int* __restrict__ partials)
{
    if (threadIdx.x == 0) {
        int run = 0;
        for (int i = 0; i < 40; i++) { int v = partials[i]; partials[i] = run; run += v; }
    }
}

__global__ __launch_bounds__(256) void scan3_kernel(
    const int* __restrict__ scanned, const int* __restrict__ partials,
    int* __restrict__ offsets, int* __restrict__ cursor)
{
    const int idx = blockIdx.x * 256 + threadIdx.x;
    if (idx < NN) {
        const int off = scanned[idx] + partials[idx >> 10];
        offsets[idx] = off;
        cursor[idx]  = off;
    }
    if (blockIdx.x == 0 && threadIdx.x == 0) offsets[NN] = EE;  // sentinel
}

// writes perm + pre-scaled src/dst streams (src*64 = hb row, dst*128 = z row)
__global__ __launch_bounds__(256) void scatter_kernel(
    const int* __restrict__ edge_index, int* __restrict__ cursor,
    int* __restrict__ perm, int* __restrict__ srcs_p, int* __restrict__ dstd_p)
{
    const int i = blockIdx.x * 256 + threadIdx.x;
    const int src = edge_index[i];
    const int dst = edge_index[EE + i];
    const int pos = atomicAdd(&cursor[dst], 1);
    perm[pos] = i;
    srcs_p[pos] = src << 6;
    dstd_p[pos] = dst << 7;
}

__global__ __launch_bounds__(256) void ea_perm_kernel(
    const float* __restrict__ edge_attr, const int* __restrict__ perm,
    float* __restrict__ ea_p)
{
    const int pos = blockIdx.x * 256 + threadIdx.x;
    const int e = perm[pos];
    const float4* sp = (const float4*)(edge_attr + (long)e * EDD);
    float4* dp = (float4*)(ea_p + (long)pos * EDD);
    dp[0] = sp[0]; dp[1] = sp[1]; dp[2] = sp[2]; dp[3] = sp[3];
}

// ---------------------------------------------------------------------------
// per-node attention partials
__global__ __launch_bounds__(256) void attn_pre_kernel(
    const float* __restrict__ h, const float* __restrict__ aW,
    float* __restrict__ pi, float* __restrict__ pj)
{
    const int wid  = threadIdx.x >> 6;
    const int lane = threadIdx.x & 63;
    const int n = blockIdx.x * 4 + wid;
    const int c0 = lane, c1 = lane + 64;
    const float h0 = h[(long)n * DD + c0], h1 = h[(long)n * DD + c1];

    float a = h0 * aW[c0]      + h1 * aW[c1];
    float b = h0 * aW[DD + c0] + h1 * aW[DD + c1];
#pragma unroll
    for (int off = 32; off > 0; off >>= 1) {
        a += __shfl_xor(a, off, 64);
        b += __shfl_xor(b, off, 64);
    }
    if (lane == 0) { pi[n] = a; pj[n] = b; }
}

// per-edge attention coefficient (streams pre-scaled; shift back)
__global__ __launch_bounds__(256) void attn_edge_kernel(
    const float* __restrict__ pi, const float* __restrict__ pj,
    const int* __restrict__ srcs_p, const int* __restrict__ dstd_p,
    const float* __restrict__ ab_p, float* __restrict__ a_p)
{
    const int idx = blockIdx.x * 256 + threadIdx.x;
    const float s = pi[dstd_p[idx] >> 7] + pj[srcs_p[idx] >> 6] + ab_p[0];
    a_p[idx] = 1.0f / (1.0f + expf(-s));
}

// ---------------------------------------------------------------------------
// Node-partitioned edge aggregation. Block owns NPB consecutive dst nodes;
// 4 waves stride the block's CSR edge range. Messages accumulate into an
// 8 KB LDS tile via LDS atomics (branchless consume, no global atomics).
// Epilogue: zb = bf16pack((1+eps)*h + acc), written once, coalesced.
__global__ __launch_bounds__(256) void edge_msg_kernel(
    const float* __restrict__ h, const unsigned* __restrict__ hb,
    const float* __restrict__ ea_p, const float* __restrict__ a_p,
    const int* __restrict__ srcs_p, const int* __restrict__ dstd_p,
    const int* __restrict__ offsets,
    const float* __restrict__ eW, const float* __restrict__ eb,
    const float* __restrict__ eps_p, unsigned* __restrict__ zb)
{
    __shared__ float lz[NPB * DD];   // 8 KB
    const int t = threadIdx.x;
    const int wid = t >> 6, lane = t & 63;
    const int nodebase = blockIdx.x * NPB;     // grid = NN/NPB

#pragma unroll
    for (int i = 0; i < NPB * DD / 256; i++) lz[t + i * 256] = 0.0f;

    float ew0[EDD], ew1[EDD];
#pragma unroll
    for (int q = 0; q < EDD; q++) {
        const float2 w2 = ((const float2*)(eW + q * DD))[lane];
        ew0[q] = w2.x; ew1[q] = w2.y;
    }
    const float2 eb2 = ((const float2*)eb)[lane];
    const float eb0 = eb2.x, eb1 = eb2.y;
    const int c0 = lane * 2, c1 = c0 + 1;

    const int estart = offsets[nodebase];
    const int eend   = offsets[nodebase + NPB];
    const int dbase  = nodebase << 7;
    __syncthreads();

#pragma unroll 2
    for (int e = estart + wid; e < eend; e += 4) {
        const int srcs = srcs_p[e];
        const int dstl = dstd_p[e] - dbase;
        const float a  = a_p[e];
        const unsigned u = hb[srcs + lane];

        const float4* eap = (const float4*)(ea_p + (long)e * EDD);
        const float4 t0 = eap[0], t1 = eap[1], t2 = eap[2], t3 = eap[3];
        float s0 = eb0, s1 = eb1;
        s0 = fmaf(t0.x, ew0[0],  s0); s1 = fmaf(t0.x, ew1[0],  s1);
        s0 = fmaf(t0.y, ew0[1],  s0); s1 = fmaf(t0.y, ew1[1],  s1);
        s0 = fmaf(t0.z, ew0[2],  s0); s1 = fmaf(t0.z, ew1[2],  s1);
        s0 = fmaf(t0.w, ew0[3],  s0); s1 = fmaf(t0.w, ew1[3],  s1);
        s0 = fmaf(t1.x, ew0[4],  s0); s1 = fmaf(t1.x, ew1[4],  s1);
        s0 = fmaf(t1.y, ew0[5],  s0); s1 = fmaf(t1.y, ew1[5],  s1);
        s0 = fmaf(t1.z, ew0[6],  s0); s1 = fmaf(t1.z, ew1[6],  s1);
        s0 = fmaf(t1.w, ew0[7],  s0); s1 = fmaf(t1.w, ew1[7],  s1);
        s0 = fmaf(t2.x, ew0[8],  s0); s1 = fmaf(t2.x, ew1[8],  s1);
        s0 = fmaf(t2.y, ew0[9],  s0); s1 = fmaf(t2.y, ew1[9],  s1);
        s0 = fmaf(t2.z, ew0[10], s0); s1 = fmaf(t2.z, ew1[10], s1);
        s0 = fmaf(t2.w, ew0[11], s0); s1 = fmaf(t2.w, ew1[11], s1);
        s0 = fmaf(t3.x, ew0[12], s0); s1 = fmaf(t3.x, ew1[12], s1);
        s0 = fmaf(t3.y, ew0[13], s0); s1 = fmaf(t3.y, ew1[13], s1);
        s0 = fmaf(t3.z, ew0[14], s0); s1 = fmaf(t3.z, ew1[14], s1);
        s0 = fmaf(t3.w, ew0[15], s0); s1 = fmaf(t3.w, ew1[15], s1);

        const float xa = __uint_as_float(u << 16);
        const float xb = __uint_as_float(u & 0xffff0000u);
        atomicAdd(&lz[dstl + c0], fmaxf(fmaf(xa, a, s0), 0.0f));
        atomicAdd(&lz[dstl + c1], fmaxf(fmaf(xb, a, s1), 0.0f));
    }
    __syncthreads();

    const float ep = 1.0f + eps_p[0];
#pragma unroll
    for (int i = 0; i < NPB * 64 / 256; i++) {
        const int idx = t + i * 256;           // uint index within tile
        const int node = idx >> 6;
        const int cp   = idx & 63;
        const long gr = (long)(nodebase + node);
        const float2 hv = ((const float2*)(h + gr * DD))[cp];
        const float v0 = fmaf(ep, hv.x, lz[node * DD + cp * 2]);
        const float v1 = fmaf(ep, hv.y, lz[node * DD + cp * 2 + 1]);
        zb[gr * 64 + cp] = pack_bf2(v0, v1);
    }
}

// ---------------------------------------------------------------------------
// Fused GIN MLP via bf16 MFMA; input is packed-bf16 zb.
__global__ __launch_bounds__(256) void mlp_mfma_kernel(
    const unsigned* __restrict__ zb,
    const unsigned short* __restrict__ w1t, const unsigned short* __restrict__ w2t,
    const float* __restrict__ b1, const float* __restrict__ g1, const float* __restrict__ bb1,
    const float* __restrict__ b2, const float* __restrict__ g2, const float* __restrict__ bb2,
    float* __restrict__ out, unsigned* __restrict__ hb, const int do_relu)
{
    __shared__ __align__(16) unsigned short zsb[64][136];   // 128 + 8 pad
    __shared__ __align__(16) unsigned short usb[64][264];   // 256 + 8 pad
    const int t = threadIdx.x;
    const int wid = t >> 6, lane = t & 63;
    const long rowbase = (long)blockIdx.x * 64;

    // stage zb (packed bf16) -> zsb
    {
        const uint4* z4 = (const uint4*)(zb + rowbase * 64);  // 16 uint4/row
#pragma unroll
        for (int i = 0; i < 4; i++) {
            const int idx = t + i * 256;       // 1024 uint4 = 64x128 bf16
            const int row = idx >> 4;
            const int q   = idx & 15;
            *(uint4*)&zsb[row][q * 8] = z4[idx];
        }
    }
    __syncthreads();

    const int mrow  = lane & 15;
    const int quad  = lane >> 4;
    const int mbase = wid * 16;
    const f32x4 vzero = {0.0f, 0.0f, 0.0f, 0.0f};

    // phase 1: C1[16 x 256] = z_tile @ W1
    bf16x8 af[4];
#pragma unroll
    for (int ks = 0; ks < 4; ks++)
        af[ks] = *(const bf16x8*)&zsb[mbase + mrow][ks * 32 + quad * 8];

    f32x4 acc[16];
#pragma unroll
    for (int i = 0; i < 16; i++) acc[i] = vzero;

#pragma unroll
    for (int nt = 0; nt < 16; nt++) {
        const unsigned short* wp = w1t + (nt * 16 + mrow) * 128 + quad * 8;
#pragma unroll
        for (int ks = 0; ks < 4; ks++) {
            const bf16x8 bfr = *(const bf16x8*)(wp + ks * 32);
            acc[nt] = __builtin_amdgcn_mfma_f32_16x16x32_bf16(af[ks], bfr, acc[nt], 0, 0, 0);
        }
    }

    // epilogue 1: bn1 + relu -> usb
#pragma unroll
    for (int nt = 0; nt < 16; nt++) {
        const int c = nt * 16 + mrow;
        const float g = g1[c], bi = b1[c], bt = bb1[c];
#pragma unroll
        for (int r = 0; r < 4; r++) {
            const int row = mbase + quad * 4 + r;
            const float u = fmaxf(fmaf(g * (acc[nt][r] + bi), kBnInv, bt), 0.0f);
            const float up = __shfl_xor(u, 1, 64);
            if ((mrow & 1) == 0)
                *(unsigned*)&usb[row][c] = pack_bf2(u, up);
        }
    }
    __syncthreads();

    // phase 2: C2[16 x 128] = u_tile @ W2
    bf16x8 af2[8];
#pragma unroll
    for (int ks = 0; ks < 8; ks++)
        af2[ks] = *(const bf16x8*)&usb[mbase + mrow][ks * 32 + quad * 8];

    f32x4 acc2[8];
#pragma unroll
    for (int i = 0; i < 8; i++) acc2[i] = vzero;

#pragma unroll
    for (int nt = 0; nt < 8; nt++) {
        const unsigned short* wp = w2t + (nt * 16 + mrow) * 256 + quad * 8;
#pragma unroll
        for (int ks = 0; ks < 8; ks++) {
            const bf16x8 bfr = *(const bf16x8*)(wp + ks * 32);
            acc2[nt] = __builtin_amdgcn_mfma_f32_16x16x32_bf16(af2[ks], bfr, acc2[nt], 0, 0, 0);
        }
    }

    // epilogue 2: bn2 (+relu) -> out fp32 + hb bf16
#pragma unroll
    for (int nt = 0; nt < 8; nt++) {
        const int c = nt * 16 + mrow;
        const float g = g2[c], bi = b2[c], bt = bb2[c];
#pragma unroll
        for (int r = 0; r < 4; r++) {
            const long row = rowbase + mbase + quad * 4 + r;
            float v = fmaf(g * (acc2[nt][r] + bi), kBnInv, bt);
            if (do_relu) v = fmaxf(v, 0.0f);
            out[row * DD + c] = v;
            const float vp = __shfl_xor(v, 1, 64);
            if ((mrow & 1) == 0)
                hb[row * 64 + (c >> 1)] = pack_bf2(v, vp);
        }
    }
}

// ---------------------------------------------------------------------------
extern "C" void kernel_launch(void* const* d_in, const int* in_sizes, int n_in,
                              void* d_out, int out_size, void* d_ws, size_t ws_size,
                              hipStream_t stream)
{
    const float* x         = (const float*)d_in[0];
    const float* edge_attr = (const float*)d_in[1];
    const float* node_W    = (const float*)d_in[2];
    const float* node_b    = (const float*)d_in[3];
    const float* edge_W    = (const float*)d_in[4];
    const float* edge_b    = (const float*)d_in[5];
    const float* attn_W    = (const float*)d_in[6];
    const float* attn_b    = (const float*)d_in[7];
    const float* eps       = (const float*)d_in[8];
    const float* W1        = (const float*)d_in[9];
    const float* b1        = (const float*)d_in[10];
    const float* bn1_g     = (const float*)d_in[11];
    const float* bn1_b     = (const float*)d_in[12];
    const float* W2        = (const float*)d_in[13];
    const float* b2        = (const float*)d_in[14];
    const float* bn_g      = (const float*)d_in[15];
    const float* bn_b      = (const float*)d_in[16];
    const int*   edge_index= (const int*)d_in[17];

    float* h    = (float*)d_ws;                          // [N*128]
    float* pi   = h + (size_t)NN * DD;                   // [N]
    float* pj   = pi + NN;                               // [N]
    float* a_p  = pj + NN;                               // [E]
    float* ea_p = a_p + EE;                              // [E*16]
    unsigned* zbuf = (unsigned*)(ea_p + (size_t)EE * EDD);           // [N*64]
    unsigned* hbuf = zbuf + (size_t)NN * 64;                         // [N*64]
    unsigned short* w1t = (unsigned short*)(hbuf + (size_t)NN * 64); // [L*32768]
    unsigned short* w2t = w1t + (size_t)LL * 32768;                  // [L*32768]
    int* counts  = (int*)(w2t + (size_t)LL * 32768);     // [N]
    int* offsets = counts + NN;                          // [N+1]
    int* cursor  = offsets + NN + 1;                     // [N]
    int* scanned = cursor + NN;                          // [40960]
    int* partials= scanned + 40960;                      // [64]
    int* perm    = partials + 64;                        // [E]
    int* srcs_p  = perm + EE;                            // [E] (src*64)
    int* dstd_p  = srcs_p + EE;                          // [E] (dst*128)
    float* out = (float*)d_out;

    node_enc_kernel<<<NN / 32, 256, 0, stream>>>(x, node_W, node_b, h, hbuf);
    wcast_kernel<<<LL * 128, 256, 0, stream>>>(W1, W2, w1t, w2t);

    hipMemsetAsync(counts, 0, NN * sizeof(int), stream);
    hist_kernel<<<EE / 256, 256, 0, stream>>>(edge_index, counts);
    scan1_kernel<<<40, 256, 0, stream>>>(counts, scanned, partials);
    scan2_kernel<<<1, 64, 0, stream>>>(partials);
    scan3_kernel<<<(NN + 255) / 256, 256, 0, stream>>>(scanned, partials, offsets, cursor);
    scatter_kernel<<<EE / 256, 256, 0, stream>>>(edge_index, cursor, perm, srcs_p, dstd_p);
    ea_perm_kernel<<<EE / 256, 256, 0, stream>>>(edge_attr, perm, ea_p);

    for (int l = 0; l < LL; l++) {
        attn_pre_kernel<<<NN / 4, 256, 0, stream>>>(h, attn_W + (size_t)l * 2 * DD, pi, pj);
        attn_edge_kernel<<<EE / 256, 256, 0, stream>>>(
            pi, pj, srcs_p, dstd_p, attn_b + l, a_p);
        edge_msg_kernel<<<NN / NPB, 256, 0, stream>>>(
            h, hbuf, ea_p, a_p, srcs_p, dstd_p, offsets,
            edge_W + (size_t)l * EDD * DD, edge_b + (size_t)l * DD,
            eps + l, zbuf);
        mlp_mfma_kernel<<<NN / 64, 256, 0, stream>>>(
            zbuf,
            w1t + (size_t)l * 32768, w2t + (size_t)l * 32768,
            b1 + (size_t)l * 2 * DD, bn1_g + (size_t)l * 2 * DD, bn1_b + (size_t)l * 2 * DD,
            b2 + (size_t)l * DD, bn_g + (size_t)l * DD, bn_b + (size_t)l * DD,
            (l == LL - 1) ? out : h, hbuf, (l < LL - 1) ? 1 : 0);
    }
}

// Round 9
// 783.504 us; speedup vs baseline: 2.2558x; 2.2558x over previous
//
#include <hip/hip_runtime.h>
#include <math.h>

#define NN 40000
#define EE 640000
#define DD 128
#define EDD 16
#define LL 3
#define CH 32   // edges per wave in edge_msg_kernel

__device__ __constant__ float kBnInv = 0.9999950000374997f; // 1/sqrt(1+1e-5)

typedef __bf16 bf16x8 __attribute__((ext_vector_type(8)));
typedef float  f32x4  __attribute__((ext_vector_type(4)));
typedef float  f32x2  __attribute__((ext_vector_type(2)));

// pack two floats to bf16 pair (RTNE) in one uint: lo16=a, hi16=b
__device__ __forceinline__ unsigned pack_bf2(float a, float b) {
    unsigned ua = __float_as_uint(a), ub = __float_as_uint(b);
    ua = (ua + 0x7fffu + ((ua >> 16) & 1u)) >> 16;
    ub = (ub + 0x7fffu + ((ub >> 16) & 1u)) & 0xffff0000u;
    return ua | ub;
}
__device__ __forceinline__ unsigned short bf16r(float x) {
    unsigned u = __float_as_uint(x);
    u = (u + 0x7fffu + ((u >> 16) & 1u)) >> 16;
    return (unsigned short)u;
}

// ---------------------------------------------------------------------------
// h = x @ node_W + node_b; also emits packed-bf16 hb
__global__ __launch_bounds__(256) void node_enc_kernel(
    const float* __restrict__ x, const float* __restrict__ W,
    const float* __restrict__ b, float* __restrict__ h,
    unsigned* __restrict__ hb)
{
    __shared__ float xs[32][DD];
    const int t = threadIdx.x;
    const long rowbase = (long)blockIdx.x * 32;

    const float4* x4 = (const float4*)(x + rowbase * DD);
    float4* xs4 = (float4*)&xs[0][0];
#pragma unroll
    for (int i = 0; i < 4; i++) xs4[t + i * 256] = x4[t + i * 256];
    __syncthreads();

    const int c  = (t & 31) * 4;
    const int r0 = (t >> 5) * 4;

    float acc[4][4] = {};
    for (int k4 = 0; k4 < DD; k4 += 4) {
        float4 xr[4];
#pragma unroll
        for (int i = 0; i < 4; i++) xr[i] = *(const float4*)&xs[r0 + i][k4];
#pragma unroll
        for (int kk = 0; kk < 4; kk++) {
            const float4 w = *(const float4*)(W + (k4 + kk) * DD + c);
#pragma unroll
            for (int i = 0; i < 4; i++) {
                const float xv = ((const float*)&xr[i])[kk];
                acc[i][0] = fmaf(xv, w.x, acc[i][0]);
                acc[i][1] = fmaf(xv, w.y, acc[i][1]);
                acc[i][2] = fmaf(xv, w.z, acc[i][2]);
                acc[i][3] = fmaf(xv, w.w, acc[i][3]);
            }
        }
    }
    const float4 bv = *(const float4*)(b + c);
#pragma unroll
    for (int i = 0; i < 4; i++) {
        const long row = rowbase + r0 + i;
        float4 ov = { acc[i][0] + bv.x, acc[i][1] + bv.y,
                      acc[i][2] + bv.z, acc[i][3] + bv.w };
        *(float4*)(h + row * DD + c) = ov;
        uint2 pv = { pack_bf2(ov.x, ov.y), pack_bf2(ov.z, ov.w) };
        *(uint2*)(hb + row * 64 + (c >> 1)) = pv;
    }
}

// ---------------------------------------------------------------------------
// weight transpose + bf16 cast
__global__ __launch_bounds__(256) void wcast_kernel(
    const float* __restrict__ W1, const float* __restrict__ W2,
    unsigned short* __restrict__ w1t, unsigned short* __restrict__ w2t)
{
    const int idx = blockIdx.x * 256 + threadIdx.x;   // grid covers LL*32768
    const int l = idx >> 15, r = idx & 32767;
    {   const int n = r >> 7, k = r & 127;
        w1t[idx] = bf16r(W1[(l << 15) + (k << 8) + n]);
    }
    {   const int n = r >> 8, k = r & 255;
        w2t[idx] = bf16r(W2[(l << 15) + (k << 7) + n]);
    }
}

// ---------------------------------------------------------------------------
// CSR build
__global__ __launch_bounds__(256) void hist_kernel(
    const int* __restrict__ edge_index, int* __restrict__ counts)
{
    const int i = blockIdx.x * 256 + threadIdx.x;
    atomicAdd(&counts[edge_index[EE + i]], 1);
}

__global__ __launch_bounds__(256) void scan1_kernel(
    const int* __restrict__ counts, int* __restrict__ scanned,
    int* __restrict__ partials)
{
    __shared__ int sdata[256];
    const int t = threadIdx.x;
    const int base = blockIdx.x * 1024 + t * 4;
    int v[4]; int sum = 0;
#pragma unroll
    for (int i = 0; i < 4; i++) {
        const int idx = base + i;
        v[i] = (idx < NN) ? counts[idx] : 0;
        sum += v[i];
    }
    sdata[t] = sum;
    __syncthreads();
    for (int off = 1; off < 256; off <<= 1) {
        int x = (t >= off) ? sdata[t - off] : 0;
        __syncthreads();
        sdata[t] += x;
        __syncthreads();
    }
    int run = sdata[t] - sum;
#pragma unroll
    for (int i = 0; i < 4; i++) {
        const int idx = base + i;
        if (idx < NN) scanned[idx] = run;
        run += v[i];
    }
    if (t == 255) partials[blockIdx.x] = sdata[255];
}

__global__ void scan2_kernel(int* __restrict__ partials)
{
    if (threadIdx.x == 0) {
        int run = 0;
        for (int i = 0; i < 40; i++) { int v = partials[i]; partials[i] = run; run += v; }
    }
}

__global__ __launch_bounds__(256) void scan3_kernel(
    const int* __restrict__ scanned, const int* __restrict__ partials,
    int* __restrict__ offsets, int* __restrict__ cursor)
{
    const int idx = blockIdx.x * 256 + threadIdx.x;
    if (idx < NN) {
        const int off = scanned[idx] + partials[idx >> 10];
        offsets[idx] = off;
        cursor[idx]  = off;
    }
}

// writes perm + pre-scaled src/dst streams (src*64 = hb row, dst*128 = z row)
__global__ __launch_bounds__(256) void scatter_kernel(
    const int* __restrict__ edge_index, int* __restrict__ cursor,
    int* __restrict__ perm, int* __restrict__ srcs_p, int* __restrict__ dstd_p)
{
    const int i = blockIdx.x * 256 + threadIdx.x;
    const int src = edge_index[i];
    const int dst = edge_index[EE + i];
    const int pos = atomicAdd(&cursor[dst], 1);
    perm[pos] = i;
    srcs_p[pos] = src << 6;
    dstd_p[pos] = dst << 7;
}

__global__ __launch_bounds__(256) void ea_perm_kernel(
    const float* __restrict__ edge_attr, const int* __restrict__ perm,
    float* __restrict__ ea_p)
{
    const int pos = blockIdx.x * 256 + threadIdx.x;
    const int e = perm[pos];
    const float4* sp = (const float4*)(edge_attr + (long)e * EDD);
    float4* dp = (float4*)(ea_p + (long)pos * EDD);
    dp[0] = sp[0]; dp[1] = sp[1]; dp[2] = sp[2]; dp[3] = sp[3];
}

// ---------------------------------------------------------------------------
// per-node attention partials + z init (z = (1+eps)*h)
__global__ __launch_bounds__(256) void attn_pre_kernel(
    const float* __restrict__ h, const float* __restrict__ aW,
    const float* __restrict__ eps_p,
    float* __restrict__ pi, float* __restrict__ pj, float* __restrict__ z)
{
    const int wid  = threadIdx.x >> 6;
    const int lane = threadIdx.x & 63;
    const int n = blockIdx.x * 4 + wid;
    const int c0 = lane, c1 = lane + 64;
    const float ep = 1.0f + eps_p[0];
    const float h0 = h[(long)n * DD + c0], h1 = h[(long)n * DD + c1];

    z[(long)n * DD + c0] = ep * h0;
    z[(long)n * DD + c1] = ep * h1;

    float a = h0 * aW[c0]      + h1 * aW[c1];
    float b = h0 * aW[DD + c0] + h1 * aW[DD + c1];
#pragma unroll
    for (int off = 32; off > 0; off >>= 1) {
        a += __shfl_xor(a, off, 64);
        b += __shfl_xor(b, off, 64);
    }
    if (lane == 0) { pi[n] = a; pj[n] = b; }
}

// per-edge attention coefficient (streams pre-scaled; shift back)
__global__ __launch_bounds__(256) void attn_edge_kernel(
    const float* __restrict__ pi, const float* __restrict__ pj,
    const int* __restrict__ srcs_p, const int* __restrict__ dstd_p,
    const float* __restrict__ ab_p, float* __restrict__ a_p)
{
    const int idx = blockIdx.x * 256 + threadIdx.x;
    const float s = pi[dstd_p[idx] >> 7] + pj[srcs_p[idx] >> 6] + ab_p[0];
    a_p[idx] = 1.0f / (1.0f + expf(-s));
}

// ---------------------------------------------------------------------------
// Edge-parallel segmented aggregation (R6 structure), batch-4 load-hoisted,
// ev chain + consume in f32x2 so the compiler emits v_pk_fma_f32.
// Lane owns cols (2*lane, 2*lane+1); h gathered as one packed-bf16 dword.
// z pre-initialized to (1+eps)*h; flush via global atomics on dst change.
__global__ __launch_bounds__(256) void edge_msg_kernel(
    const unsigned* __restrict__ hb, const float* __restrict__ ea_p,
    const float* __restrict__ a_p,
    const int* __restrict__ srcs_p, const int* __restrict__ dstd_p,
    const float* __restrict__ eW, const float* __restrict__ eb,
    float* __restrict__ z)
{
    const int wid  = threadIdx.x >> 6;
    const int lane = threadIdx.x & 63;
    const long e0  = ((long)blockIdx.x * 4 + wid) * CH;  // grid = EE/(4*CH)
    const int c0 = lane * 2;

    f32x2 ew[EDD];
#pragma unroll
    for (int q = 0; q < EDD; q++) {
        const float2 w2 = ((const float2*)(eW + q * DD))[lane];
        ew[q][0] = w2.x; ew[q][1] = w2.y;
    }
    const float2 ebf = ((const float2*)eb)[lane];
    const f32x2 ebv = { ebf.x, ebf.y };
    const f32x2 zero2 = { 0.0f, 0.0f };

    f32x2 acc = zero2;
    int cur = dstd_p[e0];

    for (int k4 = 0; k4 < CH; k4 += 4) {
        const long e = e0 + k4;

        // ---- load phase (branch-free; streams + gathers for 4 edges) ----
        const int4   dst4 = *(const int4*)(dstd_p + e);
        const int4   src4 = *(const int4*)(srcs_p + e);
        const float4 a4   = *(const float4*)(a_p + e);
        const int dd[4] = { dst4.x, dst4.y, dst4.z, dst4.w };
        const int ss[4] = { src4.x, src4.y, src4.z, src4.w };
        const float aa[4] = { a4.x, a4.y, a4.z, a4.w };

        unsigned u[4];
#pragma unroll
        for (int j = 0; j < 4; j++) u[j] = hb[ss[j] + lane];

        f32x2 ev[4];
#pragma unroll
        for (int j = 0; j < 4; j++) {
            const float4* eap = (const float4*)(ea_p + (e + j) * EDD);
            const float4 t0 = eap[0], t1 = eap[1], t2 = eap[2], t3 = eap[3];
            const float ea[EDD] = { t0.x,t0.y,t0.z,t0.w, t1.x,t1.y,t1.z,t1.w,
                                    t2.x,t2.y,t2.z,t2.w, t3.x,t3.y,t3.z,t3.w };
            f32x2 s = ebv;
#pragma unroll
            for (int q = 0; q < EDD; q++) {
                const f32x2 eaq = { ea[q], ea[q] };
                s = __builtin_elementwise_fma(eaq, ew[q], s);
            }
            ev[j] = s;
        }

        // ---- consume phase (wave-uniform branch, registers only) ----
#pragma unroll
        for (int j = 0; j < 4; j++) {
            if (dd[j] != cur) {
                atomicAdd(&z[cur + c0],     acc[0]);
                atomicAdd(&z[cur + c0 + 1], acc[1]);
                acc = zero2; cur = dd[j];
            }
            const f32x2 xj = { __uint_as_float(u[j] << 16),
                               __uint_as_float(u[j] & 0xffff0000u) };
            const f32x2 av = { aa[j], aa[j] };
            f32x2 m = __builtin_elementwise_fma(xj, av, ev[j]);
            m = __builtin_elementwise_max(m, zero2);
            acc += m;
        }
    }
    atomicAdd(&z[cur + c0],     acc[0]);
    atomicAdd(&z[cur + c0 + 1], acc[1]);
}

// ---------------------------------------------------------------------------
// Fused GIN MLP via bf16 MFMA. Block = 64 rows, 4 waves; wave owns a 16-row
// stripe. A-frags: lane m=lane&15, k=quad*8+j; B pre-transposed [n][k] bf16.
// C/D: col=lane&15, row=quad*4+reg.
__global__ __launch_bounds__(256) void mlp_mfma_kernel(
    const float* __restrict__ zin,
    const unsigned short* __restrict__ w1t, const unsigned short* __restrict__ w2t,
    const float* __restrict__ b1, const float* __restrict__ g1, const float* __restrict__ bb1,
    const float* __restrict__ b2, const float* __restrict__ g2, const float* __restrict__ bb2,
    float* __restrict__ out, unsigned* __restrict__ hb, const int do_relu)
{
    __shared__ __align__(16) unsigned short zsb[64][136];   // 128 + 8 pad
    __shared__ __align__(16) unsigned short usb[64][264];   // 256 + 8 pad
    const int t = threadIdx.x;
    const int wid = t >> 6, lane = t & 63;
    const long rowbase = (long)blockIdx.x * 64;

    // stage z (fp32) -> zsb (bf16)
    {
        const float4* z4 = (const float4*)(zin + rowbase * DD);
#pragma unroll
        for (int i = 0; i < 8; i++) {
            const int idx = t + i * 256;          // 2048 float4 = 64x128
            const float4 v = z4[idx];
            const int row = idx >> 5;
            const int c4  = (idx & 31) * 4;
            uint2 pv = { pack_bf2(v.x, v.y), pack_bf2(v.z, v.w) };
            *(uint2*)&zsb[row][c4] = pv;
        }
    }
    __syncthreads();

    const int mrow  = lane & 15;
    const int quad  = lane >> 4;
    const int mbase = wid * 16;
    const f32x4 vzero = {0.0f, 0.0f, 0.0f, 0.0f};

    // phase 1: C1[16 x 256] = z_tile @ W1
    bf16x8 af[4];
#pragma unroll
    for (int ks = 0; ks < 4; ks++)
        af[ks] = *(const bf16x8*)&zsb[mbase + mrow][ks * 32 + quad * 8];

    f32x4 acc[16];
#pragma unroll
    for (int i = 0; i < 16; i++) acc[i] = vzero;

#pragma unroll
    for (int nt = 0; nt < 16; nt++) {
        const unsigned short* wp = w1t + (nt * 16 + mrow) * 128 + quad * 8;
#pragma unroll
        for (int ks = 0; ks < 4; ks++) {
            const bf16x8 bfr = *(const bf16x8*)(wp + ks * 32);
            acc[nt] = __builtin_amdgcn_mfma_f32_16x16x32_bf16(af[ks], bfr, acc[nt], 0, 0, 0);
        }
    }

    // epilogue 1: bn1 + relu -> usb (bf16, packed pairwise via shuffle)
#pragma unroll
    for (int nt = 0; nt < 16; nt++) {
        const int c = nt * 16 + mrow;
        const float g = g1[c], bi = b1[c], bt = bb1[c];
#pragma unroll
        for (int r = 0; r < 4; r++) {
            const int row = mbase + quad * 4 + r;
            const float u = fmaxf(fmaf(g * (acc[nt][r] + bi), kBnInv, bt), 0.0f);
            const float up = __shfl_xor(u, 1, 64);
            if ((mrow & 1) == 0)
                *(unsigned*)&usb[row][c] = pack_bf2(u, up);
        }
    }
    __syncthreads();

    // phase 2: C2[16 x 128] = u_tile @ W2
    bf16x8 af2[8];
#pragma unroll
    for (int ks = 0; ks < 8; ks++)
        af2[ks] = *(const bf16x8*)&usb[mbase + mrow][ks * 32 + quad * 8];

    f32x4 acc2[8];
#pragma unroll
    for (int i = 0; i < 8; i++) acc2[i] = vzero;

#pragma unroll
    for (int nt = 0; nt < 8; nt++) {
        const unsigned short* wp = w2t + (nt * 16 + mrow) * 256 + quad * 8;
#pragma unroll
        for (int ks = 0; ks < 8; ks++) {
            const bf16x8 bfr = *(const bf16x8*)(wp + ks * 32);
            acc2[nt] = __builtin_amdgcn_mfma_f32_16x16x32_bf16(af2[ks], bfr, acc2[nt], 0, 0, 0);
        }
    }

    // epilogue 2: bn2 (+relu) -> out fp32 + hb bf16
#pragma unroll
    for (int nt = 0; nt < 8; nt++) {
        const int c = nt * 16 + mrow;
        const float g = g2[c], bi = b2[c], bt = bb2[c];
#pragma unroll
        for (int r = 0; r < 4; r++) {
            const long row = rowbase + mbase + quad * 4 + r;
            float v = fmaf(g * (acc2[nt][r] + bi), kBnInv, bt);
            if (do_relu) v = fmaxf(v, 0.0f);
            out[row * DD + c] = v;
            const float vp = __shfl_xor(v, 1, 64);
            if ((mrow & 1) == 0)
                hb[row * 64 + (c >> 1)] = pack_bf2(v, vp);
        }
    }
}

// ---------------------------------------------------------------------------
extern "C" void kernel_launch(void* const* d_in, const int* in_sizes, int n_in,
                              void* d_out, int out_size, void* d_ws, size_t ws_size,
                              hipStream_t stream)
{
    const float* x         = (const float*)d_in[0];
    const float* edge_attr = (const float*)d_in[1];
    const float* node_W    = (const float*)d_in[2];
    const float* node_b    = (const float*)d_in[3];
    const float* edge_W    = (const float*)d_in[4];
    const float* edge_b    = (const float*)d_in[5];
    const float* attn_W    = (const float*)d_in[6];
    const float* attn_b    = (const float*)d_in[7];
    const float* eps       = (const float*)d_in[8];
    const float* W1        = (const float*)d_in[9];
    const float* b1        = (const float*)d_in[10];
    const float* bn1_g     = (const float*)d_in[11];
    const float* bn1_b     = (const float*)d_in[12];
    const float* W2        = (const float*)d_in[13];
    const float* b2        = (const float*)d_in[14];
    const float* bn_g      = (const float*)d_in[15];
    const float* bn_b      = (const float*)d_in[16];
    const int*   edge_index= (const int*)d_in[17];

    float* h    = (float*)d_ws;                          // [N*D]
    float* z    = h + (size_t)NN * DD;                   // [N*D]
    float* pi   = z + (size_t)NN * DD;                   // [N]
    float* pj   = pi + NN;                               // [N]
    float* a_p  = pj + NN;                               // [E]
    float* ea_p = a_p + EE;                              // [E*16]
    unsigned* hbuf = (unsigned*)(ea_p + (size_t)EE * EDD);          // [N*64]
    unsigned short* w1t = (unsigned short*)(hbuf + (size_t)NN * 64); // [L*32768]
    unsigned short* w2t = w1t + (size_t)LL * 32768;                  // [L*32768]
    int* counts  = (int*)(w2t + (size_t)LL * 32768);     // [N]
    int* offsets = counts + NN;                          // [N]
    int* cursor  = offsets + NN;                         // [N]
    int* scanned = cursor + NN;                          // [40960]
    int* partials= scanned + 40960;                      // [64]
    int* perm    = partials + 64;                        // [E]
    int* srcs_p  = perm + EE;                            // [E] (src*64)
    int* dstd_p  = srcs_p + EE;                          // [E] (dst*128)
    float* out = (float*)d_out;

    node_enc_kernel<<<NN / 32, 256, 0, stream>>>(x, node_W, node_b, h, hbuf);
    wcast_kernel<<<LL * 128, 256, 0, stream>>>(W1, W2, w1t, w2t);

    hipMemsetAsync(counts, 0, NN * sizeof(int), stream);
    hist_kernel<<<EE / 256, 256, 0, stream>>>(edge_index, counts);
    scan1_kernel<<<40, 256, 0, stream>>>(counts, scanned, partials);
    scan2_kernel<<<1, 64, 0, stream>>>(partials);
    scan3_kernel<<<(NN + 255) / 256, 256, 0, stream>>>(scanned, partials, offsets, cursor);
    scatter_kernel<<<EE / 256, 256, 0, stream>>>(edge_index, cursor, perm, srcs_p, dstd_p);
    ea_perm_kernel<<<EE / 256, 256, 0, stream>>>(edge_attr, perm, ea_p);

    for (int l = 0; l < LL; l++) {
        attn_pre_kernel<<<NN / 4, 256, 0, stream>>>(
            h, attn_W + (size_t)l * 2 * DD, eps + l, pi, pj, z);
        attn_edge_kernel<<<EE / 256, 256, 0, stream>>>(
            pi, pj, srcs_p, dstd_p, attn_b + l, a_p);
        edge_msg_kernel<<<EE / (4 * CH), 256, 0, stream>>>(
            hbuf, ea_p, a_p, srcs_p, dstd_p,
            edge_W + (size_t)l * EDD * DD, edge_b + (size_t)l * DD, z);
        mlp_mfma_kernel<<<NN / 64, 256, 0, stream>>>(
            z,
            w1t + (size_t)l * 32768, w2t + (size_t)l * 32768,
            b1 + (size_t)l * 2 * DD, bn1_g + (size_t)l * 2 * DD, bn1_b + (size_t)l * 2 * DD,
            b2 + (size_t)l * DD, bn_g + (size_t)l * DD, bn_b + (size_t)l * DD,
            (l == LL - 1) ? out : h, hbuf, (l < LL - 1) ? 1 : 0);
    }
}

// Round 10
// 641.863 us; speedup vs baseline: 2.7536x; 1.2207x over previous
//
#include <hip/hip_runtime.h>
#include <math.h>

#define NN 40000
#define EE 640000
#define DD 128
#define EDD 16
#define LL 3
#define TEB 128   // edges per block in edge_msg_kernel

__device__ __constant__ float kBnInv = 0.9999950000374997f; // 1/sqrt(1+1e-5)

typedef __bf16 bf16x8 __attribute__((ext_vector_type(8)));
typedef float  f32x4  __attribute__((ext_vector_type(4)));
typedef float  f32x2  __attribute__((ext_vector_type(2)));

// pack two floats to bf16 pair (RTNE) in one uint: lo16=a, hi16=b
__device__ __forceinline__ unsigned pack_bf2(float a, float b) {
    unsigned ua = __float_as_uint(a), ub = __float_as_uint(b);
    ua = (ua + 0x7fffu + ((ua >> 16) & 1u)) >> 16;
    ub = (ub + 0x7fffu + ((ub >> 16) & 1u)) & 0xffff0000u;
    return ua | ub;
}
__device__ __forceinline__ unsigned short bf16r(float x) {
    unsigned u = __float_as_uint(x);
    u = (u + 0x7fffu + ((u >> 16) & 1u)) >> 16;
    return (unsigned short)u;
}

// ---------------------------------------------------------------------------
// h = x @ node_W + node_b; also emits packed-bf16 hb
__global__ __launch_bounds__(256) void node_enc_kernel(
    const float* __restrict__ x, const float* __restrict__ W,
    const float* __restrict__ b, float* __restrict__ h,
    unsigned* __restrict__ hb)
{
    __shared__ float xs[32][DD];
    const int t = threadIdx.x;
    const long rowbase = (long)blockIdx.x * 32;

    const float4* x4 = (const float4*)(x + rowbase * DD);
    float4* xs4 = (float4*)&xs[0][0];
#pragma unroll
    for (int i = 0; i < 4; i++) xs4[t + i * 256] = x4[t + i * 256];
    __syncthreads();

    const int c  = (t & 31) * 4;
    const int r0 = (t >> 5) * 4;

    float acc[4][4] = {};
    for (int k4 = 0; k4 < DD; k4 += 4) {
        float4 xr[4];
#pragma unroll
        for (int i = 0; i < 4; i++) xr[i] = *(const float4*)&xs[r0 + i][k4];
#pragma unroll
        for (int kk = 0; kk < 4; kk++) {
            const float4 w = *(const float4*)(W + (k4 + kk) * DD + c);
#pragma unroll
            for (int i = 0; i < 4; i++) {
                const float xv = ((const float*)&xr[i])[kk];
                acc[i][0] = fmaf(xv, w.x, acc[i][0]);
                acc[i][1] = fmaf(xv, w.y, acc[i][1]);
                acc[i][2] = fmaf(xv, w.z, acc[i][2]);
                acc[i][3] = fmaf(xv, w.w, acc[i][3]);
            }
        }
    }
    const float4 bv = *(const float4*)(b + c);
#pragma unroll
    for (int i = 0; i < 4; i++) {
        const long row = rowbase + r0 + i;
        float4 ov = { acc[i][0] + bv.x, acc[i][1] + bv.y,
                      acc[i][2] + bv.z, acc[i][3] + bv.w };
        *(float4*)(h + row * DD + c) = ov;
        uint2 pv = { pack_bf2(ov.x, ov.y), pack_bf2(ov.z, ov.w) };
        *(uint2*)(hb + row * 64 + (c >> 1)) = pv;
    }
}

// ---------------------------------------------------------------------------
// weight transpose + bf16 cast
__global__ __launch_bounds__(256) void wcast_kernel(
    const float* __restrict__ W1, const float* __restrict__ W2,
    unsigned short* __restrict__ w1t, unsigned short* __restrict__ w2t)
{
    const int idx = blockIdx.x * 256 + threadIdx.x;   // grid covers LL*32768
    const int l = idx >> 15, r = idx & 32767;
    {   const int n = r >> 7, k = r & 127;
        w1t[idx] = bf16r(W1[(l << 15) + (k << 8) + n]);
    }
    {   const int n = r >> 8, k = r & 255;
        w2t[idx] = bf16r(W2[(l << 15) + (k << 7) + n]);
    }
}

// ---------------------------------------------------------------------------
// CSR build
__global__ __launch_bounds__(256) void hist_kernel(
    const int* __restrict__ edge_index, int* __restrict__ counts)
{
    const int i = blockIdx.x * 256 + threadIdx.x;
    atomicAdd(&counts[edge_index[EE + i]], 1);
}

__global__ __launch_bounds__(256) void scan1_kernel(
    const int* __restrict__ counts, int* __restrict__ scanned,
    int* __restrict__ partials)
{
    __shared__ int sdata[256];
    const int t = threadIdx.x;
    const int base = blockIdx.x * 1024 + t * 4;
    int v[4]; int sum = 0;
#pragma unroll
    for (int i = 0; i < 4; i++) {
        const int idx = base + i;
        v[i] = (idx < NN) ? counts[idx] : 0;
        sum += v[i];
    }
    sdata[t] = sum;
    __syncthreads();
    for (int off = 1; off < 256; off <<= 1) {
        int x = (t >= off) ? sdata[t - off] : 0;
        __syncthreads();
        sdata[t] += x;
        __syncthreads();
    }
    int run = sdata[t] - sum;
#pragma unroll
    for (int i = 0; i < 4; i++) {
        const int idx = base + i;
        if (idx < NN) scanned[idx] = run;
        run += v[i];
    }
    if (t == 255) partials[blockIdx.x] = sdata[255];
}

__global__ void scan2_kernel(int* __restrict__ partials)
{
    if (threadIdx.x == 0) {
        int run = 0;
        for (int i = 0; i < 40; i++) { int v = partials[i]; partials[i] = run; run += v; }
    }
}

__global__ __launch_bounds__(256) void scan3_kernel(
    const int* __restrict__ scanned, const int* __restrict__ partials,
    int* __restrict__ offsets, int* __restrict__ cursor)
{
    const int idx = blockIdx.x * 256 + threadIdx.x;
    if (idx < NN) {
        const int off = scanned[idx] + partials[idx >> 10];
        offsets[idx] = off;
        cursor[idx]  = off;
    }
}

// writes perm + pre-scaled src/dst streams (src*64 = hb row, dst*128 = z row)
__global__ __launch_bounds__(256) void scatter_kernel(
    const int* __restrict__ edge_index, int* __restrict__ cursor,
    int* __restrict__ perm, int* __restrict__ srcs_p, int* __restrict__ dstd_p)
{
    const int i = blockIdx.x * 256 + threadIdx.x;
    const int src = edge_index[i];
    const int dst = edge_index[EE + i];
    const int pos = atomicAdd(&cursor[dst], 1);
    perm[pos] = i;
    srcs_p[pos] = src << 6;
    dstd_p[pos] = dst << 7;
}

__global__ __launch_bounds__(256) void ea_perm_kernel(
    const float* __restrict__ edge_attr, const int* __restrict__ perm,
    float* __restrict__ ea_p)
{
    const int pos = blockIdx.x * 256 + threadIdx.x;
    const int e = perm[pos];
    const float4* sp = (const float4*)(edge_attr + (long)e * EDD);
    float4* dp = (float4*)(ea_p + (long)pos * EDD);
    dp[0] = sp[0]; dp[1] = sp[1]; dp[2] = sp[2]; dp[3] = sp[3];
}

// ---------------------------------------------------------------------------
// per-node attention partials + z init (z = (1+eps)*h)
__global__ __launch_bounds__(256) void attn_pre_kernel(
    const float* __restrict__ h, const float* __restrict__ aW,
    const float* __restrict__ eps_p,
    float* __restrict__ pi, float* __restrict__ pj, float* __restrict__ z)
{
    const int wid  = threadIdx.x >> 6;
    const int lane = threadIdx.x & 63;
    const int n = blockIdx.x * 4 + wid;
    const int c0 = lane, c1 = lane + 64;
    const float ep = 1.0f + eps_p[0];
    const float h0 = h[(long)n * DD + c0], h1 = h[(long)n * DD + c1];

    z[(long)n * DD + c0] = ep * h0;
    z[(long)n * DD + c1] = ep * h1;

    float a = h0 * aW[c0]      + h1 * aW[c1];
    float b = h0 * aW[DD + c0] + h1 * aW[DD + c1];
#pragma unroll
    for (int off = 32; off > 0; off >>= 1) {
        a += __shfl_xor(a, off, 64);
        b += __shfl_xor(b, off, 64);
    }
    if (lane == 0) { pi[n] = a; pj[n] = b; }
}

// ---------------------------------------------------------------------------
// LDS-staged edge aggregation. Block owns TEB=128 consecutive CSR edges.
// Stage: meta (+fused sigmoid), hb rows (coalesced 16-thr/row gathers, 8
// independent loads/thread in flight), ea stream -> LDS (42.5 KB, 3 blk/CU).
// Consume: wave w processes edges [w*32, w*32+32) entirely from LDS;
// segmented register accumulate, atomic flush to z on dst change.
__global__ __launch_bounds__(256) void edge_msg_kernel(
    const unsigned* __restrict__ hb, const float* __restrict__ ea_p,
    const float* __restrict__ pi, const float* __restrict__ pj,
    const int* __restrict__ srcs_p, const int* __restrict__ dstd_p,
    const float* __restrict__ ab_p,
    const float* __restrict__ eW, const float* __restrict__ eb,
    float* __restrict__ z)
{
    __shared__ unsigned sh_hb[TEB * 64];     // 32 KB
    __shared__ float    sh_ea[TEB * EDD];    // 8 KB
    __shared__ int      sh_src[TEB];
    __shared__ int      sh_dst[TEB];
    __shared__ float    sh_a[TEB];

    const int t = threadIdx.x;
    const long e0 = (long)blockIdx.x * TEB;   // grid = EE/TEB

    // ---- meta stage + fused attention coefficient ----
    if (t < TEB) {
        const int ss = srcs_p[e0 + t];
        const int dd = dstd_p[e0 + t];
        sh_src[t] = ss;
        sh_dst[t] = dd;
        const float s = pi[dd >> 7] + pj[ss >> 6] + ab_p[0];
        sh_a[t] = 1.0f / (1.0f + expf(-s));
    }
    __syncthreads();

    // ---- gather + stream stage ----
    {
        const int chunk = t & 15;            // dword4 index within row
        const int r0    = t >> 4;            // 0..15
#pragma unroll
        for (int i = 0; i < TEB / 16; i++) { // 8 independent gathers/thread
            const int row  = r0 + 16 * i;
            const int srow = sh_src[row];    // src*64 (dword index)
            *(uint4*)&sh_hb[row * 64 + chunk * 4] =
                *(const uint4*)(hb + srow + chunk * 4);
        }
        const float4* g = (const float4*)(ea_p + e0 * EDD); // 512 float4
        float4* l = (float4*)sh_ea;
        l[t]       = g[t];
        l[t + 256] = g[t + 256];
    }
    __syncthreads();

    // ---- consume (all from LDS) ----
    const int wid = t >> 6, lane = t & 63;
    const int c0 = lane * 2;
    const int base = wid * (TEB / 4);        // 32 edges per wave

    f32x2 ew[EDD];
#pragma unroll
    for (int q = 0; q < EDD; q++) {
        const float2 w2 = ((const float2*)(eW + q * DD))[lane];
        ew[q][0] = w2.x; ew[q][1] = w2.y;
    }
    const float2 ebf = ((const float2*)eb)[lane];
    const f32x2 ebv = { ebf.x, ebf.y };
    const f32x2 zero2 = { 0.0f, 0.0f };

    f32x2 acc = zero2;
    int cur = sh_dst[base];

#pragma unroll 4
    for (int j = 0; j < TEB / 4; j++) {
        const int   dd = sh_dst[base + j];
        const float a  = sh_a[base + j];
        const unsigned u = sh_hb[(base + j) * 64 + lane];

        const float4* eap = (const float4*)&sh_ea[(base + j) * EDD];
        const float4 t0 = eap[0], t1 = eap[1], t2 = eap[2], t3 = eap[3];
        const float ea[EDD] = { t0.x,t0.y,t0.z,t0.w, t1.x,t1.y,t1.z,t1.w,
                                t2.x,t2.y,t2.z,t2.w, t3.x,t3.y,t3.z,t3.w };
        f32x2 ev = ebv;
#pragma unroll
        for (int q = 0; q < EDD; q++) {
            const f32x2 eaq = { ea[q], ea[q] };
            ev = __builtin_elementwise_fma(eaq, ew[q], ev);
        }

        if (dd != cur) {                     // wave-uniform branch
            atomicAdd(&z[cur + c0],     acc[0]);
            atomicAdd(&z[cur + c0 + 1], acc[1]);
            acc = zero2; cur = dd;
        }
        const f32x2 xj = { __uint_as_float(u << 16),
                           __uint_as_float(u & 0xffff0000u) };
        const f32x2 av = { a, a };
        f32x2 m = __builtin_elementwise_fma(xj, av, ev);
        m = __builtin_elementwise_max(m, zero2);
        acc += m;
    }
    atomicAdd(&z[cur + c0],     acc[0]);
    atomicAdd(&z[cur + c0 + 1], acc[1]);
}

// ---------------------------------------------------------------------------
// Fused GIN MLP via bf16 MFMA. Block = 64 rows, 4 waves; wave owns a 16-row
// stripe. A-frags: lane m=lane&15, k=quad*8+j; B pre-transposed [n][k] bf16.
// C/D: col=lane&15, row=quad*4+reg.
__global__ __launch_bounds__(256) void mlp_mfma_kernel(
    const float* __restrict__ zin,
    const unsigned short* __restrict__ w1t, const unsigned short* __restrict__ w2t,
    const float* __restrict__ b1, const float* __restrict__ g1, const float* __restrict__ bb1,
    const float* __restrict__ b2, const float* __restrict__ g2, const float* __restrict__ bb2,
    float* __restrict__ out, unsigned* __restrict__ hb, const int do_relu)
{
    __shared__ __align__(16) unsigned short zsb[64][136];   // 128 + 8 pad
    __shared__ __align__(16) unsigned short usb[64][264];   // 256 + 8 pad
    const int t = threadIdx.x;
    const int wid = t >> 6, lane = t & 63;
    const long rowbase = (long)blockIdx.x * 64;

    // stage z (fp32) -> zsb (bf16)
    {
        const float4* z4 = (const float4*)(zin + rowbase * DD);
#pragma unroll
        for (int i = 0; i < 8; i++) {
            const int idx = t + i * 256;          // 2048 float4 = 64x128
            const float4 v = z4[idx];
            const int row = idx >> 5;
            const int c4  = (idx & 31) * 4;
            uint2 pv = { pack_bf2(v.x, v.y), pack_bf2(v.z, v.w) };
            *(uint2*)&zsb[row][c4] = pv;
        }
    }
    __syncthreads();

    const int mrow  = lane & 15;
    const int quad  = lane >> 4;
    const int mbase = wid * 16;
    const f32x4 vzero = {0.0f, 0.0f, 0.0f, 0.0f};

    // phase 1: C1[16 x 256] = z_tile @ W1
    bf16x8 af[4];
#pragma unroll
    for (int ks = 0; ks < 4; ks++)
        af[ks] = *(const bf16x8*)&zsb[mbase + mrow][ks * 32 + quad * 8];

    f32x4 acc[16];
#pragma unroll
    for (int i = 0; i < 16; i++) acc[i] = vzero;

#pragma unroll
    for (int nt = 0; nt < 16; nt++) {
        const unsigned short* wp = w1t + (nt * 16 + mrow) * 128 + quad * 8;
#pragma unroll
        for (int ks = 0; ks < 4; ks++) {
            const bf16x8 bfr = *(const bf16x8*)(wp + ks * 32);
            acc[nt] = __builtin_amdgcn_mfma_f32_16x16x32_bf16(af[ks], bfr, acc[nt], 0, 0, 0);
        }
    }

    // epilogue 1: bn1 + relu -> usb (bf16, packed pairwise via shuffle)
#pragma unroll
    for (int nt = 0; nt < 16; nt++) {
        const int c = nt * 16 + mrow;
        const float g = g1[c], bi = b1[c], bt = bb1[c];
#pragma unroll
        for (int r = 0; r < 4; r++) {
            const int row = mbase + quad * 4 + r;
            const float u = fmaxf(fmaf(g * (acc[nt][r] + bi), kBnInv, bt), 0.0f);
            const float up = __shfl_xor(u, 1, 64);
            if ((mrow & 1) == 0)
                *(unsigned*)&usb[row][c] = pack_bf2(u, up);
        }
    }
    __syncthreads();

    // phase 2: C2[16 x 128] = u_tile @ W2
    bf16x8 af2[8];
#pragma unroll
    for (int ks = 0; ks < 8; ks++)
        af2[ks] = *(const bf16x8*)&usb[mbase + mrow][ks * 32 + quad * 8];

    f32x4 acc2[8];
#pragma unroll
    for (int i = 0; i < 8; i++) acc2[i] = vzero;

#pragma unroll
    for (int nt = 0; nt < 8; nt++) {
        const unsigned short* wp = w2t + (nt * 16 + mrow) * 256 + quad * 8;
#pragma unroll
        for (int ks = 0; ks < 8; ks++) {
            const bf16x8 bfr = *(const bf16x8*)(wp + ks * 32);
            acc2[nt] = __builtin_amdgcn_mfma_f32_16x16x32_bf16(af2[ks], bfr, acc2[nt], 0, 0, 0);
        }
    }

    // epilogue 2: bn2 (+relu) -> out fp32 + hb bf16
#pragma unroll
    for (int nt = 0; nt < 8; nt++) {
        const int c = nt * 16 + mrow;
        const float g = g2[c], bi = b2[c], bt = bb2[c];
#pragma unroll
        for (int r = 0; r < 4; r++) {
            const long row = rowbase + mbase + quad * 4 + r;
            float v = fmaf(g * (acc2[nt][r] + bi), kBnInv, bt);
            if (do_relu) v = fmaxf(v, 0.0f);
            out[row * DD + c] = v;
            const float vp = __shfl_xor(v, 1, 64);
            if ((mrow & 1) == 0)
                hb[row * 64 + (c >> 1)] = pack_bf2(v, vp);
        }
    }
}

// ---------------------------------------------------------------------------
extern "C" void kernel_launch(void* const* d_in, const int* in_sizes, int n_in,
                              void* d_out, int out_size, void* d_ws, size_t ws_size,
                              hipStream_t stream)
{
    const float* x         = (const float*)d_in[0];
    const float* edge_attr = (const float*)d_in[1];
    const float* node_W    = (const float*)d_in[2];
    const float* node_b    = (const float*)d_in[3];
    const float* edge_W    = (const float*)d_in[4];
    const float* edge_b    = (const float*)d_in[5];
    const float* attn_W    = (const float*)d_in[6];
    const float* attn_b    = (const float*)d_in[7];
    const float* eps       = (const float*)d_in[8];
    const float* W1        = (const float*)d_in[9];
    const float* b1        = (const float*)d_in[10];
    const float* bn1_g     = (const float*)d_in[11];
    const float* bn1_b     = (const float*)d_in[12];
    const float* W2        = (const float*)d_in[13];
    const float* b2        = (const float*)d_in[14];
    const float* bn_g      = (const float*)d_in[15];
    const float* bn_b      = (const float*)d_in[16];
    const int*   edge_index= (const int*)d_in[17];

    float* h    = (float*)d_ws;                          // [N*D]
    float* z    = h + (size_t)NN * DD;                   // [N*D]
    float* pi   = z + (size_t)NN * DD;                   // [N]
    float* pj   = pi + NN;                               // [N]
    float* ea_p = pj + NN;                               // [E*16]
    unsigned* hbuf = (unsigned*)(ea_p + (size_t)EE * EDD);          // [N*64]
    unsigned short* w1t = (unsigned short*)(hbuf + (size_t)NN * 64); // [L*32768]
    unsigned short* w2t = w1t + (size_t)LL * 32768;                  // [L*32768]
    int* counts  = (int*)(w2t + (size_t)LL * 32768);     // [N]
    int* offsets = counts + NN;                          // [N]
    int* cursor  = offsets + NN;                         // [N]
    int* scanned = cursor + NN;                          // [40960]
    int* partials= scanned + 40960;                      // [64]
    int* perm    = partials + 64;                        // [E]
    int* srcs_p  = perm + EE;                            // [E] (src*64)
    int* dstd_p  = srcs_p + EE;                          // [E] (dst*128)
    float* out = (float*)d_out;

    node_enc_kernel<<<NN / 32, 256, 0, stream>>>(x, node_W, node_b, h, hbuf);
    wcast_kernel<<<LL * 128, 256, 0, stream>>>(W1, W2, w1t, w2t);

    hipMemsetAsync(counts, 0, NN * sizeof(int), stream);
    hist_kernel<<<EE / 256, 256, 0, stream>>>(edge_index, counts);
    scan1_kernel<<<40, 256, 0, stream>>>(counts, scanned, partials);
    scan2_kernel<<<1, 64, 0, stream>>>(partials);
    scan3_kernel<<<(NN + 255) / 256, 256, 0, stream>>>(scanned, partials, offsets, cursor);
    scatter_kernel<<<EE / 256, 256, 0, stream>>>(edge_index, cursor, perm, srcs_p, dstd_p);
    ea_perm_kernel<<<EE / 256, 256, 0, stream>>>(edge_attr, perm, ea_p);

    for (int l = 0; l < LL; l++) {
        attn_pre_kernel<<<NN / 4, 256, 0, stream>>>(
            h, attn_W + (size_t)l * 2 * DD, eps + l, pi, pj, z);
        edge_msg_kernel<<<EE / TEB, 256, 0, stream>>>(
            hbuf, ea_p, pi, pj, srcs_p, dstd_p, attn_b + l,
            edge_W + (size_t)l * EDD * DD, edge_b + (size_t)l * DD, z);
        mlp_mfma_kernel<<<NN / 64, 256, 0, stream>>>(
            z,
            w1t + (size_t)l * 32768, w2t + (size_t)l * 32768,
            b1 + (size_t)l * 2 * DD, bn1_g + (size_t)l * 2 * DD, bn1_b + (size_t)l * 2 * DD,
            b2 + (size_t)l * DD, bn_g + (size_t)l * DD, bn_b + (size_t)l * DD,
            (l == LL - 1) ? out : h, hbuf, (l < LL - 1) ? 1 : 0);
    }
}

// Round 11
// 588.653 us; speedup vs baseline: 3.0025x; 1.0904x over previous
//
#include <hip/hip_runtime.h>
#include <math.h>

#define NN 40000
#define EE 640000
#define DD 128
#define EDD 16
#define LL 3
#define TEB 128   // edges per block in edge_msg_kernel

__device__ __constant__ float kBnInv = 0.9999950000374997f; // 1/sqrt(1+1e-5)

typedef __bf16 bf16x8 __attribute__((ext_vector_type(8)));
typedef float  f32x4  __attribute__((ext_vector_type(4)));
typedef float  f32x2  __attribute__((ext_vector_type(2)));

// pack two floats to bf16 pair (RTNE) in one uint: lo16=a, hi16=b
__device__ __forceinline__ unsigned pack_bf2(float a, float b) {
    unsigned ua = __float_as_uint(a), ub = __float_as_uint(b);
    ua = (ua + 0x7fffu + ((ua >> 16) & 1u)) >> 16;
    ub = (ub + 0x7fffu + ((ub >> 16) & 1u)) & 0xffff0000u;
    return ua | ub;
}
__device__ __forceinline__ unsigned short bf16r(float x) {
    unsigned u = __float_as_uint(x);
    u = (u + 0x7fffu + ((u >> 16) & 1u)) >> 16;
    return (unsigned short)u;
}

// ---------------------------------------------------------------------------
// h = x @ node_W + node_b; emits h (fp32), hb (packed bf16), and the fused
// layer-0 attention partials pi/pj + z init (= (1+eps0)*h).
__global__ __launch_bounds__(256) void node_enc_kernel(
    const float* __restrict__ x, const float* __restrict__ W,
    const float* __restrict__ b,
    const float* __restrict__ aW, const float* __restrict__ eps_p,
    float* __restrict__ h, unsigned* __restrict__ hb,
    float* __restrict__ pi, float* __restrict__ pj, float* __restrict__ z)
{
    __shared__ float xs[32][DD];
    const int t = threadIdx.x;
    const long rowbase = (long)blockIdx.x * 32;

    const float4* x4 = (const float4*)(x + rowbase * DD);
    float4* xs4 = (float4*)&xs[0][0];
#pragma unroll
    for (int i = 0; i < 4; i++) xs4[t + i * 256] = x4[t + i * 256];
    __syncthreads();

    const int c  = (t & 31) * 4;
    const int r0 = (t >> 5) * 4;

    float acc[4][4] = {};
    for (int k4 = 0; k4 < DD; k4 += 4) {
        float4 xr[4];
#pragma unroll
        for (int i = 0; i < 4; i++) xr[i] = *(const float4*)&xs[r0 + i][k4];
#pragma unroll
        for (int kk = 0; kk < 4; kk++) {
            const float4 w = *(const float4*)(W + (k4 + kk) * DD + c);
#pragma unroll
            for (int i = 0; i < 4; i++) {
                const float xv = ((const float*)&xr[i])[kk];
                acc[i][0] = fmaf(xv, w.x, acc[i][0]);
                acc[i][1] = fmaf(xv, w.y, acc[i][1]);
                acc[i][2] = fmaf(xv, w.z, acc[i][2]);
                acc[i][3] = fmaf(xv, w.w, acc[i][3]);
            }
        }
    }
    const float4 bv  = *(const float4*)(b + c);
    const float4 awi = *(const float4*)(aW + c);
    const float4 awj = *(const float4*)(aW + DD + c);
    const float ep = 1.0f + eps_p[0];

    float pa[4], pb[4];
#pragma unroll
    for (int i = 0; i < 4; i++) {
        const long row = rowbase + r0 + i;
        float4 ov = { acc[i][0] + bv.x, acc[i][1] + bv.y,
                      acc[i][2] + bv.z, acc[i][3] + bv.w };
        *(float4*)(h + row * DD + c) = ov;
        uint2 pv = { pack_bf2(ov.x, ov.y), pack_bf2(ov.z, ov.w) };
        *(uint2*)(hb + row * 64 + (c >> 1)) = pv;
        float4 zv = { ep * ov.x, ep * ov.y, ep * ov.z, ep * ov.w };
        *(float4*)(z + row * DD + c) = zv;
        pa[i] = ov.x * awi.x + ov.y * awi.y + ov.z * awi.z + ov.w * awi.w;
        pb[i] = ov.x * awj.x + ov.y * awj.y + ov.z * awj.z + ov.w * awj.w;
    }
    // reduce over the 32 lanes sharing a row group (lane bits 0-4)
#pragma unroll
    for (int off = 1; off < 32; off <<= 1) {
#pragma unroll
        for (int i = 0; i < 4; i++) {
            pa[i] += __shfl_xor(pa[i], off, 64);
            pb[i] += __shfl_xor(pb[i], off, 64);
        }
    }
    if ((t & 31) == 0) {
#pragma unroll
        for (int i = 0; i < 4; i++) {
            pi[rowbase + r0 + i] = pa[i];
            pj[rowbase + r0 + i] = pb[i];
        }
    }
}

// ---------------------------------------------------------------------------
// weight transpose + bf16 cast
__global__ __launch_bounds__(256) void wcast_kernel(
    const float* __restrict__ W1, const float* __restrict__ W2,
    unsigned short* __restrict__ w1t, unsigned short* __restrict__ w2t)
{
    const int idx = blockIdx.x * 256 + threadIdx.x;   // grid covers LL*32768
    const int l = idx >> 15, r = idx & 32767;
    {   const int n = r >> 7, k = r & 127;
        w1t[idx] = bf16r(W1[(l << 15) + (k << 8) + n]);
    }
    {   const int n = r >> 8, k = r & 255;
        w2t[idx] = bf16r(W2[(l << 15) + (k << 7) + n]);
    }
}

// ---------------------------------------------------------------------------
// CSR build
__global__ __launch_bounds__(256) void hist_kernel(
    const int* __restrict__ edge_index, int* __restrict__ counts)
{
    const int i = blockIdx.x * 256 + threadIdx.x;
    atomicAdd(&counts[edge_index[EE + i]], 1);
}

__global__ __launch_bounds__(256) void scan1_kernel(
    const int* __restrict__ counts, int* __restrict__ scanned,
    int* __restrict__ partials)
{
    __shared__ int sdata[256];
    const int t = threadIdx.x;
    const int base = blockIdx.x * 1024 + t * 4;
    int v[4]; int sum = 0;
#pragma unroll
    for (int i = 0; i < 4; i++) {
        const int idx = base + i;
        v[i] = (idx < NN) ? counts[idx] : 0;
        sum += v[i];
    }
    sdata[t] = sum;
    __syncthreads();
    for (int off = 1; off < 256; off <<= 1) {
        int x = (t >= off) ? sdata[t - off] : 0;
        __syncthreads();
        sdata[t] += x;
        __syncthreads();
    }
    int run = sdata[t] - sum;
#pragma unroll
    for (int i = 0; i < 4; i++) {
        const int idx = base + i;
        if (idx < NN) scanned[idx] = run;
        run += v[i];
    }
    if (t == 255) partials[blockIdx.x] = sdata[255];
}

__global__ void scan2_kernel(int* __restrict__ partials)
{
    if (threadIdx.x == 0) {
        int run = 0;
        for (int i = 0; i < 40; i++) { int v = partials[i]; partials[i] = run; run += v; }
    }
}

__global__ __launch_bounds__(256) void scan3_kernel(
    const int* __restrict__ scanned, const int* __restrict__ partials,
    int* __restrict__ offsets, int* __restrict__ cursor)
{
    const int idx = blockIdx.x * 256 + threadIdx.x;
    if (idx < NN) {
        const int off = scanned[idx] + partials[idx >> 10];
        offsets[idx] = off;
        cursor[idx]  = off;
    }
}

// scatter: writes pre-scaled src/dst streams AND the bf16-packed edge_attr
// row directly at its CSR position (sequential reads, scattered writes).
__global__ __launch_bounds__(256) void scatter_kernel(
    const int* __restrict__ edge_index, const float* __restrict__ edge_attr,
    int* __restrict__ cursor,
    int* __restrict__ srcs_p, int* __restrict__ dstd_p,
    unsigned* __restrict__ ea_b)
{
    const int i = blockIdx.x * 256 + threadIdx.x;
    const int src = edge_index[i];
    const int dst = edge_index[EE + i];
    const int pos = atomicAdd(&cursor[dst], 1);
    srcs_p[pos] = src << 6;
    dstd_p[pos] = dst << 7;

    const float4* sp = (const float4*)(edge_attr + (long)i * EDD);
    const float4 s0 = sp[0], s1 = sp[1], s2 = sp[2], s3 = sp[3];
    uint4 o0 = { pack_bf2(s0.x, s0.y), pack_bf2(s0.z, s0.w),
                 pack_bf2(s1.x, s1.y), pack_bf2(s1.z, s1.w) };
    uint4 o1 = { pack_bf2(s2.x, s2.y), pack_bf2(s2.z, s2.w),
                 pack_bf2(s3.x, s3.y), pack_bf2(s3.z, s3.w) };
    *(uint4*)(ea_b + (long)pos * 8)     = o0;
    *(uint4*)(ea_b + (long)pos * 8 + 4) = o1;
}

// ---------------------------------------------------------------------------
// LDS-staged edge aggregation (R10 structure, ea now packed bf16 -> 37.5 KB
// LDS -> 4 blocks/CU). Block owns TEB=128 consecutive CSR edges.
__global__ __launch_bounds__(256) void edge_msg_kernel(
    const unsigned* __restrict__ hb, const unsigned* __restrict__ ea_b,
    const float* __restrict__ pi, const float* __restrict__ pj,
    const int* __restrict__ srcs_p, const int* __restrict__ dstd_p,
    const float* __restrict__ ab_p,
    const float* __restrict__ eW, const float* __restrict__ eb,
    float* __restrict__ z)
{
    __shared__ unsigned sh_hb[TEB * 64];     // 32 KB
    __shared__ unsigned sh_ea[TEB * 8];      // 4 KB (bf16-packed)
    __shared__ int      sh_src[TEB];
    __shared__ int      sh_dst[TEB];
    __shared__ float    sh_a[TEB];

    const int t = threadIdx.x;
    const long e0 = (long)blockIdx.x * TEB;   // grid = EE/TEB

    // ---- meta stage + fused attention coefficient ----
    if (t < TEB) {
        const int ss = srcs_p[e0 + t];
        const int dd = dstd_p[e0 + t];
        sh_src[t] = ss;
        sh_dst[t] = dd;
        const float s = pi[dd >> 7] + pj[ss >> 6] + ab_p[0];
        sh_a[t] = 1.0f / (1.0f + expf(-s));
    }
    __syncthreads();

    // ---- gather + stream stage ----
    {
        const int chunk = t & 15;            // dword4 index within row
        const int r0    = t >> 4;            // 0..15
#pragma unroll
        for (int i = 0; i < TEB / 16; i++) { // 8 independent gathers/thread
            const int row  = r0 + 16 * i;
            const int srow = sh_src[row];    // src*64 (dword index)
            *(uint4*)&sh_hb[row * 64 + chunk * 4] =
                *(const uint4*)(hb + srow + chunk * 4);
        }
        ((uint4*)sh_ea)[t] = ((const uint4*)(ea_b + e0 * 8))[t]; // 256 uint4
    }
    __syncthreads();

    // ---- consume (all from LDS) ----
    const int wid = t >> 6, lane = t & 63;
    const int c0 = lane * 2;
    const int base = wid * (TEB / 4);        // 32 edges per wave

    f32x2 ew[EDD];
#pragma unroll
    for (int q = 0; q < EDD; q++) {
        const float2 w2 = ((const float2*)(eW + q * DD))[lane];
        ew[q][0] = w2.x; ew[q][1] = w2.y;
    }
    const float2 ebf = ((const float2*)eb)[lane];
    const f32x2 ebv = { ebf.x, ebf.y };
    const f32x2 zero2 = { 0.0f, 0.0f };

    f32x2 acc = zero2;
    int cur = sh_dst[base];

#pragma unroll 4
    for (int j = 0; j < TEB / 4; j++) {
        const int   dd = sh_dst[base + j];
        const float a  = sh_a[base + j];
        const unsigned u = sh_hb[(base + j) * 64 + lane];

        const uint4 ua = *(const uint4*)&sh_ea[(base + j) * 8];
        const uint4 ub = *(const uint4*)&sh_ea[(base + j) * 8 + 4];
        const unsigned es[8] = { ua.x, ua.y, ua.z, ua.w,
                                 ub.x, ub.y, ub.z, ub.w };
        f32x2 ev = ebv;
#pragma unroll
        for (int q = 0; q < 8; q++) {
            const float f0 = __uint_as_float(es[q] << 16);
            const float f1 = __uint_as_float(es[q] & 0xffff0000u);
            const f32x2 v0 = { f0, f0 }, v1 = { f1, f1 };
            ev = __builtin_elementwise_fma(v0, ew[2 * q],     ev);
            ev = __builtin_elementwise_fma(v1, ew[2 * q + 1], ev);
        }

        if (dd != cur) {                     // wave-uniform branch
            atomicAdd(&z[cur + c0],     acc[0]);
            atomicAdd(&z[cur + c0 + 1], acc[1]);
            acc = zero2; cur = dd;
        }
        const f32x2 xj = { __uint_as_float(u << 16),
                           __uint_as_float(u & 0xffff0000u) };
        const f32x2 av = { a, a };
        f32x2 m = __builtin_elementwise_fma(xj, av, ev);
        m = __builtin_elementwise_max(m, zero2);
        acc += m;
    }
    atomicAdd(&z[cur + c0],     acc[0]);
    atomicAdd(&z[cur + c0 + 1], acc[1]);
}

// ---------------------------------------------------------------------------
// Fused GIN MLP via bf16 MFMA. Block = 64 rows, 4 waves. Epilogue 2 also
// produces (when do_relu) the NEXT layer's pi/pj partials and z init.
__global__ __launch_bounds__(256) void mlp_mfma_kernel(
    const float* __restrict__ zin,
    const unsigned short* __restrict__ w1t, const unsigned short* __restrict__ w2t,
    const float* __restrict__ b1, const float* __restrict__ g1, const float* __restrict__ bb1,
    const float* __restrict__ b2, const float* __restrict__ g2, const float* __restrict__ bb2,
    const float* __restrict__ aWn, const float* __restrict__ epsn_p,
    float* __restrict__ out, unsigned* __restrict__ hb,
    float* __restrict__ pi, float* __restrict__ pj, float* __restrict__ z,
    const int do_relu)
{
    __shared__ __align__(16) unsigned short zsb[64][136];   // 128 + 8 pad
    __shared__ __align__(16) unsigned short usb[64][264];   // 256 + 8 pad
    const int t = threadIdx.x;
    const int wid = t >> 6, lane = t & 63;
    const long rowbase = (long)blockIdx.x * 64;

    // stage z (fp32) -> zsb (bf16)
    {
        const float4* z4 = (const float4*)(zin + rowbase * DD);
#pragma unroll
        for (int i = 0; i < 8; i++) {
            const int idx = t + i * 256;          // 2048 float4 = 64x128
            const float4 v = z4[idx];
            const int row = idx >> 5;
            const int c4  = (idx & 31) * 4;
            uint2 pv = { pack_bf2(v.x, v.y), pack_bf2(v.z, v.w) };
            *(uint2*)&zsb[row][c4] = pv;
        }
    }
    __syncthreads();

    const int mrow  = lane & 15;
    const int quad  = lane >> 4;
    const int mbase = wid * 16;
    const f32x4 vzero = {0.0f, 0.0f, 0.0f, 0.0f};

    // phase 1: C1[16 x 256] = z_tile @ W1
    bf16x8 af[4];
#pragma unroll
    for (int ks = 0; ks < 4; ks++)
        af[ks] = *(const bf16x8*)&zsb[mbase + mrow][ks * 32 + quad * 8];

    f32x4 acc[16];
#pragma unroll
    for (int i = 0; i < 16; i++) acc[i] = vzero;

#pragma unroll
    for (int nt = 0; nt < 16; nt++) {
        const unsigned short* wp = w1t + (nt * 16 + mrow) * 128 + quad * 8;
#pragma unroll
        for (int ks = 0; ks < 4; ks++) {
            const bf16x8 bfr = *(const bf16x8*)(wp + ks * 32);
            acc[nt] = __builtin_amdgcn_mfma_f32_16x16x32_bf16(af[ks], bfr, acc[nt], 0, 0, 0);
        }
    }

    // epilogue 1: bn1 + relu -> usb
#pragma unroll
    for (int nt = 0; nt < 16; nt++) {
        const int c = nt * 16 + mrow;
        const float g = g1[c], bi = b1[c], bt = bb1[c];
#pragma unroll
        for (int r = 0; r < 4; r++) {
            const int row = mbase + quad * 4 + r;
            const float u = fmaxf(fmaf(g * (acc[nt][r] + bi), kBnInv, bt), 0.0f);
            const float up = __shfl_xor(u, 1, 64);
            if ((mrow & 1) == 0)
                *(unsigned*)&usb[row][c] = pack_bf2(u, up);
        }
    }
    __syncthreads();

    // phase 2: C2[16 x 128] = u_tile @ W2
    bf16x8 af2[8];
#pragma unroll
    for (int ks = 0; ks < 8; ks++)
        af2[ks] = *(const bf16x8*)&usb[mbase + mrow][ks * 32 + quad * 8];

    f32x4 acc2[8];
#pragma unroll
    for (int i = 0; i < 8; i++) acc2[i] = vzero;

#pragma unroll
    for (int nt = 0; nt < 8; nt++) {
        const unsigned short* wp = w2t + (nt * 16 + mrow) * 256 + quad * 8;
#pragma unroll
        for (int ks = 0; ks < 8; ks++) {
            const bf16x8 bfr = *(const bf16x8*)(wp + ks * 32);
            acc2[nt] = __builtin_amdgcn_mfma_f32_16x16x32_bf16(af2[ks], bfr, acc2[nt], 0, 0, 0);
        }
    }

    // epilogue 2: bn2 (+relu) -> out fp32 + hb bf16 (+ next-layer pi/pj/z)
    float awn_i[8], awn_j[8];
    float epn = 0.0f;
    if (do_relu) {
#pragma unroll
        for (int nt = 0; nt < 8; nt++) {
            awn_i[nt] = aWn[nt * 16 + mrow];
            awn_j[nt] = aWn[DD + nt * 16 + mrow];
        }
        epn = 1.0f + epsn_p[0];
    }
    float si[4] = {0, 0, 0, 0}, sj[4] = {0, 0, 0, 0};

#pragma unroll
    for (int nt = 0; nt < 8; nt++) {
        const int c = nt * 16 + mrow;
        const float g = g2[c], bi = b2[c], bt = bb2[c];
#pragma unroll
        for (int r = 0; r < 4; r++) {
            const long row = rowbase + mbase + quad * 4 + r;
            float v = fmaf(g * (acc2[nt][r] + bi), kBnInv, bt);
            if (do_relu) {
                v = fmaxf(v, 0.0f);
                z[row * DD + c] = epn * v;
                si[r] = fmaf(v, awn_i[nt], si[r]);
                sj[r] = fmaf(v, awn_j[nt], sj[r]);
            }
            out[row * DD + c] = v;
            const float vp = __shfl_xor(v, 1, 64);
            if ((mrow & 1) == 0)
                hb[row * 64 + (c >> 1)] = pack_bf2(v, vp);
        }
    }
    if (do_relu) {
#pragma unroll
        for (int off = 1; off < 16; off <<= 1) {
#pragma unroll
            for (int r = 0; r < 4; r++) {
                si[r] += __shfl_xor(si[r], off, 64);
                sj[r] += __shfl_xor(sj[r], off, 64);
            }
        }
        if (mrow == 0) {
#pragma unroll
            for (int r = 0; r < 4; r++) {
                const long row = rowbase + mbase + quad * 4 + r;
                pi[row] = si[r];
                pj[row] = sj[r];
            }
        }
    }
}

// ---------------------------------------------------------------------------
extern "C" void kernel_launch(void* const* d_in, const int* in_sizes, int n_in,
                              void* d_out, int out_size, void* d_ws, size_t ws_size,
                              hipStream_t stream)
{
    const float* x         = (const float*)d_in[0];
    const float* edge_attr = (const float*)d_in[1];
    const float* node_W    = (const float*)d_in[2];
    const float* node_b    = (const float*)d_in[3];
    const float* edge_W    = (const float*)d_in[4];
    const float* edge_b    = (const float*)d_in[5];
    const float* attn_W    = (const float*)d_in[6];
    const float* attn_b    = (const float*)d_in[7];
    const float* eps       = (const float*)d_in[8];
    const float* W1        = (const float*)d_in[9];
    const float* b1        = (const float*)d_in[10];
    const float* bn1_g     = (const float*)d_in[11];
    const float* bn1_b     = (const float*)d_in[12];
    const float* W2        = (const float*)d_in[13];
    const float* b2        = (const float*)d_in[14];
    const float* bn_g      = (const float*)d_in[15];
    const float* bn_b      = (const float*)d_in[16];
    const int*   edge_index= (const int*)d_in[17];

    float* h    = (float*)d_ws;                          // [N*D]
    float* z    = h + (size_t)NN * DD;                   // [N*D]
    float* pi   = z + (size_t)NN * DD;                   // [N]
    float* pj   = pi + NN;                               // [N]
    unsigned* ea_b = (unsigned*)(pj + NN);               // [E*8] packed bf16
    unsigned* hbuf = ea_b + (size_t)EE * 8;              // [N*64]
    unsigned short* w1t = (unsigned short*)(hbuf + (size_t)NN * 64); // [L*32768]
    unsigned short* w2t = w1t + (size_t)LL * 32768;                  // [L*32768]
    int* counts  = (int*)(w2t + (size_t)LL * 32768);     // [N]
    int* offsets = counts + NN;                          // [N]
    int* cursor  = offsets + NN;                         // [N]
    int* scanned = cursor + NN;                          // [40960]
    int* partials= scanned + 40960;                      // [64]
    int* srcs_p  = partials + 64;                        // [E] (src*64)
    int* dstd_p  = srcs_p + EE;                          // [E] (dst*128)
    float* out = (float*)d_out;

    node_enc_kernel<<<NN / 32, 256, 0, stream>>>(
        x, node_W, node_b, attn_W, eps, h, hbuf, pi, pj, z);
    wcast_kernel<<<LL * 128, 256, 0, stream>>>(W1, W2, w1t, w2t);

    hipMemsetAsync(counts, 0, NN * sizeof(int), stream);
    hist_kernel<<<EE / 256, 256, 0, stream>>>(edge_index, counts);
    scan1_kernel<<<40, 256, 0, stream>>>(counts, scanned, partials);
    scan2_kernel<<<1, 64, 0, stream>>>(partials);
    scan3_kernel<<<(NN + 255) / 256, 256, 0, stream>>>(scanned, partials, offsets, cursor);
    scatter_kernel<<<EE / 256, 256, 0, stream>>>(
        edge_index, edge_attr, cursor, srcs_p, dstd_p, ea_b);

    for (int l = 0; l < LL; l++) {
        const int ln = (l + 1 < LL) ? (l + 1) : l;   // next-layer attn/eps (dummy at last)
        edge_msg_kernel<<<EE / TEB, 256, 0, stream>>>(
            hbuf, ea_b, pi, pj, srcs_p, dstd_p, attn_b + l,
            edge_W + (size_t)l * EDD * DD, edge_b + (size_t)l * DD, z);
        mlp_mfma_kernel<<<NN / 64, 256, 0, stream>>>(
            z,
            w1t + (size_t)l * 32768, w2t + (size_t)l * 32768,
            b1 + (size_t)l * 2 * DD, bn1_g + (size_t)l * 2 * DD, bn1_b + (size_t)l * 2 * DD,
            b2 + (size_t)l * DD, bn_g + (size_t)l * DD, bn_b + (size_t)l * DD,
            attn_W + (size_t)ln * 2 * DD, eps + ln,
            (l == LL - 1) ? out : h, hbuf, pi, pj, z, (l < LL - 1) ? 1 : 0);
    }
}

// Round 12
// 522.549 us; speedup vs baseline: 3.3823x; 1.1265x over previous
//
#include <hip/hip_runtime.h>
#include <math.h>

#define NN 40000
#define EE 640000
#define DD 128
#define EDD 16
#define LL 3
#define TEB 64   // edges per block in edge_msg_kernel

__device__ __constant__ float kBnInv = 0.9999950000374997f; // 1/sqrt(1+1e-5)

typedef __bf16 bf16x8 __attribute__((ext_vector_type(8)));
typedef float  f32x4  __attribute__((ext_vector_type(4)));
typedef float  f32x2  __attribute__((ext_vector_type(2)));

// pack two floats to bf16 pair (RTNE) in one uint: lo16=a, hi16=b
__device__ __forceinline__ unsigned pack_bf2(float a, float b) {
    unsigned ua = __float_as_uint(a), ub = __float_as_uint(b);
    ua = (ua + 0x7fffu + ((ua >> 16) & 1u)) >> 16;
    ub = (ub + 0x7fffu + ((ub >> 16) & 1u)) & 0xffff0000u;
    return ua | ub;
}
__device__ __forceinline__ unsigned short bf16r(float x) {
    unsigned u = __float_as_uint(x);
    u = (u + 0x7fffu + ((u >> 16) & 1u)) >> 16;
    return (unsigned short)u;
}

// ---------------------------------------------------------------------------
// h = x @ node_W + node_b; emits h (fp32), hb (packed bf16), and the fused
// layer-0 attention partials pi/pj + z init (= (1+eps0)*h).
__global__ __launch_bounds__(256) void node_enc_kernel(
    const float* __restrict__ x, const float* __restrict__ W,
    const float* __restrict__ b,
    const float* __restrict__ aW, const float* __restrict__ eps_p,
    float* __restrict__ h, unsigned* __restrict__ hb,
    float* __restrict__ pi, float* __restrict__ pj, float* __restrict__ z)
{
    __shared__ float xs[32][DD];
    const int t = threadIdx.x;
    const long rowbase = (long)blockIdx.x * 32;

    const float4* x4 = (const float4*)(x + rowbase * DD);
    float4* xs4 = (float4*)&xs[0][0];
#pragma unroll
    for (int i = 0; i < 4; i++) xs4[t + i * 256] = x4[t + i * 256];
    __syncthreads();

    const int c  = (t & 31) * 4;
    const int r0 = (t >> 5) * 4;

    float acc[4][4] = {};
    for (int k4 = 0; k4 < DD; k4 += 4) {
        float4 xr[4];
#pragma unroll
        for (int i = 0; i < 4; i++) xr[i] = *(const float4*)&xs[r0 + i][k4];
#pragma unroll
        for (int kk = 0; kk < 4; kk++) {
            const float4 w = *(const float4*)(W + (k4 + kk) * DD + c);
#pragma unroll
            for (int i = 0; i < 4; i++) {
                const float xv = ((const float*)&xr[i])[kk];
                acc[i][0] = fmaf(xv, w.x, acc[i][0]);
                acc[i][1] = fmaf(xv, w.y, acc[i][1]);
                acc[i][2] = fmaf(xv, w.z, acc[i][2]);
                acc[i][3] = fmaf(xv, w.w, acc[i][3]);
            }
        }
    }
    const float4 bv  = *(const float4*)(b + c);
    const float4 awi = *(const float4*)(aW + c);
    const float4 awj = *(const float4*)(aW + DD + c);
    const float ep = 1.0f + eps_p[0];

    float pa[4], pb[4];
#pragma unroll
    for (int i = 0; i < 4; i++) {
        const long row = rowbase + r0 + i;
        float4 ov = { acc[i][0] + bv.x, acc[i][1] + bv.y,
                      acc[i][2] + bv.z, acc[i][3] + bv.w };
        *(float4*)(h + row * DD + c) = ov;
        uint2 pv = { pack_bf2(ov.x, ov.y), pack_bf2(ov.z, ov.w) };
        *(uint2*)(hb + row * 64 + (c >> 1)) = pv;
        float4 zv = { ep * ov.x, ep * ov.y, ep * ov.z, ep * ov.w };
        *(float4*)(z + row * DD + c) = zv;
        pa[i] = ov.x * awi.x + ov.y * awi.y + ov.z * awi.z + ov.w * awi.w;
        pb[i] = ov.x * awj.x + ov.y * awj.y + ov.z * awj.z + ov.w * awj.w;
    }
#pragma unroll
    for (int off = 1; off < 32; off <<= 1) {
#pragma unroll
        for (int i = 0; i < 4; i++) {
            pa[i] += __shfl_xor(pa[i], off, 64);
            pb[i] += __shfl_xor(pb[i], off, 64);
        }
    }
    if ((t & 31) == 0) {
#pragma unroll
        for (int i = 0; i < 4; i++) {
            pi[rowbase + r0 + i] = pa[i];
            pj[rowbase + r0 + i] = pb[i];
        }
    }
}

// ---------------------------------------------------------------------------
// weight transpose + bf16 cast
__global__ __launch_bounds__(256) void wcast_kernel(
    const float* __restrict__ W1, const float* __restrict__ W2,
    unsigned short* __restrict__ w1t, unsigned short* __restrict__ w2t)
{
    const int idx = blockIdx.x * 256 + threadIdx.x;   // grid covers LL*32768
    const int l = idx >> 15, r = idx & 32767;
    {   const int n = r >> 7, k = r & 127;
        w1t[idx] = bf16r(W1[(l << 15) + (k << 8) + n]);
    }
    {   const int n = r >> 8, k = r & 255;
        w2t[idx] = bf16r(W2[(l << 15) + (k << 7) + n]);
    }
}

// ---------------------------------------------------------------------------
// CSR build
__global__ __launch_bounds__(256) void hist_kernel(
    const int* __restrict__ edge_index, int* __restrict__ counts)
{
    const int i = blockIdx.x * 256 + threadIdx.x;
    atomicAdd(&counts[edge_index[EE + i]], 1);
}

__global__ __launch_bounds__(256) void scan1_kernel(
    const int* __restrict__ counts, int* __restrict__ scanned,
    int* __restrict__ partials)
{
    __shared__ int sdata[256];
    const int t = threadIdx.x;
    const int base = blockIdx.x * 1024 + t * 4;
    int v[4]; int sum = 0;
#pragma unroll
    for (int i = 0; i < 4; i++) {
        const int idx = base + i;
        v[i] = (idx < NN) ? counts[idx] : 0;
        sum += v[i];
    }
    sdata[t] = sum;
    __syncthreads();
    for (int off = 1; off < 256; off <<= 1) {
        int x = (t >= off) ? sdata[t - off] : 0;
        __syncthreads();
        sdata[t] += x;
        __syncthreads();
    }
    int run = sdata[t] - sum;
#pragma unroll
    for (int i = 0; i < 4; i++) {
        const int idx = base + i;
        if (idx < NN) scanned[idx] = run;
        run += v[i];
    }
    if (t == 255) partials[blockIdx.x] = sdata[255];
}

__global__ void scan2_kernel(int* __restrict__ partials)
{
    if (threadIdx.x == 0) {
        int run = 0;
        for (int i = 0; i < 40; i++) { int v = partials[i]; partials[i] = run; run += v; }
    }
}

__global__ __launch_bounds__(256) void scan3_kernel(
    const int* __restrict__ scanned, const int* __restrict__ partials,
    int* __restrict__ offsets, int* __restrict__ cursor)
{
    const int idx = blockIdx.x * 256 + threadIdx.x;
    if (idx < NN) {
        const int off = scanned[idx] + partials[idx >> 10];
        offsets[idx] = off;
        cursor[idx]  = off;
    }
}

// scatter: pre-scaled src/dst streams + bf16-packed edge_attr at CSR position
__global__ __launch_bounds__(256) void scatter_kernel(
    const int* __restrict__ edge_index, const float* __restrict__ edge_attr,
    int* __restrict__ cursor,
    int* __restrict__ srcs_p, int* __restrict__ dstd_p,
    unsigned* __restrict__ ea_b)
{
    const int i = blockIdx.x * 256 + threadIdx.x;
    const int src = edge_index[i];
    const int dst = edge_index[EE + i];
    const int pos = atomicAdd(&cursor[dst], 1);
    srcs_p[pos] = src << 6;
    dstd_p[pos] = dst << 7;

    const float4* sp = (const float4*)(edge_attr + (long)i * EDD);
    const float4 s0 = sp[0], s1 = sp[1], s2 = sp[2], s3 = sp[3];
    uint4 o0 = { pack_bf2(s0.x, s0.y), pack_bf2(s0.z, s0.w),
                 pack_bf2(s1.x, s1.y), pack_bf2(s1.z, s1.w) };
    uint4 o1 = { pack_bf2(s2.x, s2.y), pack_bf2(s2.z, s2.w),
                 pack_bf2(s3.x, s3.y), pack_bf2(s3.z, s3.w) };
    *(uint4*)(ea_b + (long)pos * 8)     = o0;
    *(uint4*)(ea_b + (long)pos * 8 + 4) = o1;
}

// ---------------------------------------------------------------------------
// LDS-staged edge aggregation, TEB=64 (~21 KB LDS -> 7 blocks/CU).
// ea unpacked bf16->fp32 ONCE at stage (consume loop is pure pk-fma).
__global__ __launch_bounds__(256) void edge_msg_kernel(
    const unsigned* __restrict__ hb, const unsigned* __restrict__ ea_b,
    const float* __restrict__ pi, const float* __restrict__ pj,
    const int* __restrict__ srcs_p, const int* __restrict__ dstd_p,
    const float* __restrict__ ab_p,
    const float* __restrict__ eW, const float* __restrict__ eb,
    float* __restrict__ z)
{
    __shared__ unsigned sh_hb[TEB * 64];     // 16 KB
    __shared__ float    sh_ea[TEB * EDD];    // 4 KB (fp32, unpacked at stage)
    __shared__ int      sh_src[TEB];
    __shared__ int      sh_dst[TEB];
    __shared__ float    sh_a[TEB];

    const int t = threadIdx.x;
    const long e0 = (long)blockIdx.x * TEB;   // grid = EE/TEB

    // ---- meta stage + fused attention coefficient ----
    if (t < TEB) {
        const int ss = srcs_p[e0 + t];
        const int dd = dstd_p[e0 + t];
        sh_src[t] = ss;
        sh_dst[t] = dd;
        const float s = pi[dd >> 7] + pj[ss >> 6] + ab_p[0];
        sh_a[t] = 1.0f / (1.0f + expf(-s));
    }
    __syncthreads();

    // ---- gather + stream stage ----
    {
        const int chunk = t & 15;            // dword4 index within row
        const int r0    = t >> 4;            // 0..15
#pragma unroll
        for (int i = 0; i < TEB / 16; i++) { // 4 independent gathers/thread
            const int row  = r0 + 16 * i;
            const int srow = sh_src[row];    // src*64 (dword index)
            *(uint4*)&sh_hb[row * 64 + chunk * 4] =
                *(const uint4*)(hb + srow + chunk * 4);
        }
        // ea: 64 edges x 8 uints = 512; 2 per thread, unpack to fp32
#pragma unroll
        for (int i = 0; i < 2; i++) {
            const int idx  = t * 2 + i;          // 0..511
            const int edge = idx >> 3, q = idx & 7;
            const unsigned u = ea_b[e0 * 8 + idx];
            float2 f = { __uint_as_float(u << 16),
                         __uint_as_float(u & 0xffff0000u) };
            *(float2*)&sh_ea[edge * EDD + q * 2] = f;
        }
    }
    __syncthreads();

    // ---- consume (all from LDS) ----
    const int wid = t >> 6, lane = t & 63;
    const int c0 = lane * 2;
    const int base = wid * (TEB / 4);        // 16 edges per wave

    f32x2 ew[EDD];
#pragma unroll
    for (int q = 0; q < EDD; q++) {
        const float2 w2 = ((const float2*)(eW + q * DD))[lane];
        ew[q][0] = w2.x; ew[q][1] = w2.y;
    }
    const float2 ebf = ((const float2*)eb)[lane];
    const f32x2 ebv = { ebf.x, ebf.y };
    const f32x2 zero2 = { 0.0f, 0.0f };

    f32x2 acc = zero2;
    int cur = sh_dst[base];

#pragma unroll 4
    for (int j = 0; j < TEB / 4; j++) {
        const int   dd = sh_dst[base + j];
        const float a  = sh_a[base + j];
        const unsigned u = sh_hb[(base + j) * 64 + lane];

        const float4* eap = (const float4*)&sh_ea[(base + j) * EDD];
        const float4 t0 = eap[0], t1 = eap[1], t2 = eap[2], t3 = eap[3];
        const float ea[EDD] = { t0.x,t0.y,t0.z,t0.w, t1.x,t1.y,t1.z,t1.w,
                                t2.x,t2.y,t2.z,t2.w, t3.x,t3.y,t3.z,t3.w };
        f32x2 ev = ebv;
#pragma unroll
        for (int q = 0; q < EDD; q++) {
            const f32x2 eaq = { ea[q], ea[q] };
            ev = __builtin_elementwise_fma(eaq, ew[q], ev);
        }

        if (dd != cur) {                     // wave-uniform branch
            atomicAdd(&z[cur + c0],     acc[0]);
            atomicAdd(&z[cur + c0 + 1], acc[1]);
            acc = zero2; cur = dd;
        }
        const f32x2 xj = { __uint_as_float(u << 16),
                           __uint_as_float(u & 0xffff0000u) };
        const f32x2 av = { a, a };
        f32x2 m = __builtin_elementwise_fma(xj, av, ev);
        m = __builtin_elementwise_max(m, zero2);
        acc += m;
    }
    atomicAdd(&z[cur + c0],     acc[0]);
    atomicAdd(&z[cur + c0 + 1], acc[1]);
}

// ---------------------------------------------------------------------------
// Fused GIN MLP via bf16 MFMA, N-SPLIT: each wave owns 4 col-tiles (phase 1)
// / 2 col-tiles (phase 2) for ALL 64 rows -> no cross-wave weight redundancy.
// Epilogue 2 also produces next-layer pi/pj (LDS-reduced) and z init.
__global__ __launch_bounds__(256) void mlp_mfma_kernel(
    const float* __restrict__ zin,
    const unsigned short* __restrict__ w1t, const unsigned short* __restrict__ w2t,
    const float* __restrict__ b1, const float* __restrict__ g1, const float* __restrict__ bb1,
    const float* __restrict__ b2, const float* __restrict__ g2, const float* __restrict__ bb2,
    const float* __restrict__ aWn, const float* __restrict__ epsn_p,
    float* __restrict__ out, unsigned* __restrict__ hb,
    float* __restrict__ pi, float* __restrict__ pj, float* __restrict__ z,
    const int do_relu)
{
    __shared__ __align__(16) unsigned short zsb[64][136];   // 128 + 8 pad
    __shared__ __align__(16) unsigned short usb[64][264];   // 256 + 8 pad
    __shared__ float sh_pi[64], sh_pj[64];
    const int t = threadIdx.x;
    const int wid = t >> 6, lane = t & 63;
    const long rowbase = (long)blockIdx.x * 64;

    if (t < 64) { sh_pi[t] = 0.0f; sh_pj[t] = 0.0f; }

    // stage z (fp32) -> zsb (bf16)
    {
        const float4* z4 = (const float4*)(zin + rowbase * DD);
#pragma unroll
        for (int i = 0; i < 8; i++) {
            const int idx = t + i * 256;          // 2048 float4 = 64x128
            const float4 v = z4[idx];
            const int row = idx >> 5;
            const int c4  = (idx & 31) * 4;
            uint2 pv = { pack_bf2(v.x, v.y), pack_bf2(v.z, v.w) };
            *(uint2*)&zsb[row][c4] = pv;
        }
    }
    __syncthreads();

    const int mrow  = lane & 15;
    const int quad  = lane >> 4;
    const f32x4 vzero = {0.0f, 0.0f, 0.0f, 0.0f};

    // ---- phase 1: wave owns nt = wid*4 .. wid*4+3 (cols) for all 64 rows ----
    {
        const int nt0 = wid * 4;
        bf16x8 bf[4][4];                      // [j][ks]
#pragma unroll
        for (int j = 0; j < 4; j++) {
            const unsigned short* wp = w1t + ((nt0 + j) * 16 + mrow) * 128 + quad * 8;
#pragma unroll
            for (int ks = 0; ks < 4; ks++)
                bf[j][ks] = *(const bf16x8*)(wp + ks * 32);
        }
        float gg[4], bi[4], bt[4];
#pragma unroll
        for (int j = 0; j < 4; j++) {
            const int c = (nt0 + j) * 16 + mrow;
            gg[j] = g1[c]; bi[j] = b1[c]; bt[j] = bb1[c];
        }
#pragma unroll
        for (int rt = 0; rt < 4; rt++) {
            bf16x8 af[4];
#pragma unroll
            for (int ks = 0; ks < 4; ks++)
                af[ks] = *(const bf16x8*)&zsb[rt * 16 + mrow][ks * 32 + quad * 8];
            f32x4 acc[4];
#pragma unroll
            for (int j = 0; j < 4; j++) acc[j] = vzero;
#pragma unroll
            for (int j = 0; j < 4; j++)
#pragma unroll
                for (int ks = 0; ks < 4; ks++)
                    acc[j] = __builtin_amdgcn_mfma_f32_16x16x32_bf16(af[ks], bf[j][ks], acc[j], 0, 0, 0);
            // epilogue 1 for this row tile
#pragma unroll
            for (int j = 0; j < 4; j++) {
                const int c = (nt0 + j) * 16 + mrow;
#pragma unroll
                for (int r = 0; r < 4; r++) {
                    const int row = rt * 16 + quad * 4 + r;
                    const float u = fmaxf(fmaf(gg[j] * (acc[j][r] + bi[j]), kBnInv, bt[j]), 0.0f);
                    const float up = __shfl_xor(u, 1, 64);
                    if ((mrow & 1) == 0)
                        *(unsigned*)&usb[row][c] = pack_bf2(u, up);
                }
            }
        }
    }
    __syncthreads();

    // ---- phase 2: wave owns nt = wid*2, wid*2+1 for all 64 rows ----
    {
        const int nt0 = wid * 2;
        bf16x8 bf[2][8];
#pragma unroll
        for (int j = 0; j < 2; j++) {
            const unsigned short* wp = w2t + ((nt0 + j) * 16 + mrow) * 256 + quad * 8;
#pragma unroll
            for (int ks = 0; ks < 8; ks++)
                bf[j][ks] = *(const bf16x8*)(wp + ks * 32);
        }
        float gg[2], bi[2], bt[2], awi[2], awj[2];
#pragma unroll
        for (int j = 0; j < 2; j++) {
            const int c = (nt0 + j) * 16 + mrow;
            gg[j] = g2[c]; bi[j] = b2[c]; bt[j] = bb2[c];
            awi[j] = aWn[c]; awj[j] = aWn[DD + c];
        }
        const float epn = do_relu ? (1.0f + epsn_p[0]) : 0.0f;

#pragma unroll
        for (int rt = 0; rt < 4; rt++) {
            bf16x8 af[8];
#pragma unroll
            for (int ks = 0; ks < 8; ks++)
                af[ks] = *(const bf16x8*)&usb[rt * 16 + mrow][ks * 32 + quad * 8];
            f32x4 acc[2];
            acc[0] = vzero; acc[1] = vzero;
#pragma unroll
            for (int j = 0; j < 2; j++)
#pragma unroll
                for (int ks = 0; ks < 8; ks++)
                    acc[j] = __builtin_amdgcn_mfma_f32_16x16x32_bf16(af[ks], bf[j][ks], acc[j], 0, 0, 0);

            float si[4] = {0, 0, 0, 0}, sj[4] = {0, 0, 0, 0};
#pragma unroll
            for (int j = 0; j < 2; j++) {
                const int c = (nt0 + j) * 16 + mrow;
#pragma unroll
                for (int r = 0; r < 4; r++) {
                    const long row = rowbase + rt * 16 + quad * 4 + r;
                    float v = fmaf(gg[j] * (acc[j][r] + bi[j]), kBnInv, bt[j]);
                    if (do_relu) {
                        v = fmaxf(v, 0.0f);
                        z[row * DD + c] = epn * v;
                        si[r] = fmaf(v, awi[j], si[r]);
                        sj[r] = fmaf(v, awj[j], sj[r]);
                    }
                    out[row * DD + c] = v;
                    const float vp = __shfl_xor(v, 1, 64);
                    if ((mrow & 1) == 0)
                        hb[row * 64 + (c >> 1)] = pack_bf2(v, vp);
                }
            }
            if (do_relu) {
#pragma unroll
                for (int off = 1; off < 16; off <<= 1) {
#pragma unroll
                    for (int r = 0; r < 4; r++) {
                        si[r] += __shfl_xor(si[r], off, 64);
                        sj[r] += __shfl_xor(sj[r], off, 64);
                    }
                }
                if (mrow == 0) {
#pragma unroll
                    for (int r = 0; r < 4; r++) {
                        atomicAdd(&sh_pi[rt * 16 + quad * 4 + r], si[r]);
                        atomicAdd(&sh_pj[rt * 16 + quad * 4 + r], sj[r]);
                    }
                }
            }
        }
    }
    if (do_relu) {
        __syncthreads();
        if (t < 64) {
            pi[rowbase + t] = sh_pi[t];
            pj[rowbase + t] = sh_pj[t];
        }
    }
}

// ---------------------------------------------------------------------------
extern "C" void kernel_launch(void* const* d_in, const int* in_sizes, int n_in,
                              void* d_out, int out_size, void* d_ws, size_t ws_size,
                              hipStream_t stream)
{
    const float* x         = (const float*)d_in[0];
    const float* edge_attr = (const float*)d_in[1];
    const float* node_W    = (const float*)d_in[2];
    const float* node_b    = (const float*)d_in[3];
    const float* edge_W    = (const float*)d_in[4];
    const float* edge_b    = (const float*)d_in[5];
    const float* attn_W    = (const float*)d_in[6];
    const float* attn_b    = (const float*)d_in[7];
    const float* eps       = (const float*)d_in[8];
    const float* W1        = (const float*)d_in[9];
    const float* b1        = (const float*)d_in[10];
    const float* bn1_g     = (const float*)d_in[11];
    const float* bn1_b     = (const float*)d_in[12];
    const float* W2        = (const float*)d_in[13];
    const float* b2        = (const float*)d_in[14];
    const float* bn_g      = (const float*)d_in[15];
    const float* bn_b      = (const float*)d_in[16];
    const int*   edge_index= (const int*)d_in[17];

    float* h    = (float*)d_ws;                          // [N*D]
    float* z    = h + (size_t)NN * DD;                   // [N*D]
    float* pi   = z + (size_t)NN * DD;                   // [N]
    float* pj   = pi + NN;                               // [N]
    unsigned* ea_b = (unsigned*)(pj + NN);               // [E*8] packed bf16
    unsigned* hbuf = ea_b + (size_t)EE * 8;              // [N*64]
    unsigned short* w1t = (unsigned short*)(hbuf + (size_t)NN * 64); // [L*32768]
    unsigned short* w2t = w1t + (size_t)LL * 32768;                  // [L*32768]
    int* counts  = (int*)(w2t + (size_t)LL * 32768);     // [N]
    int* offsets = counts + NN;                          // [N]
    int* cursor  = offsets + NN;                         // [N]
    int* scanned = cursor + NN;                          // [40960]
    int* partials= scanned + 40960;                      // [64]
    int* srcs_p  = partials + 64;                        // [E] (src*64)
    int* dstd_p  = srcs_p + EE;                          // [E] (dst*128)
    float* out = (float*)d_out;

    node_enc_kernel<<<NN / 32, 256, 0, stream>>>(
        x, node_W, node_b, attn_W, eps, h, hbuf, pi, pj, z);
    wcast_kernel<<<LL * 128, 256, 0, stream>>>(W1, W2, w1t, w2t);

    hipMemsetAsync(counts, 0, NN * sizeof(int), stream);
    hist_kernel<<<EE / 256, 256, 0, stream>>>(edge_index, counts);
    scan1_kernel<<<40, 256, 0, stream>>>(counts, scanned, partials);
    scan2_kernel<<<1, 64, 0, stream>>>(partials);
    scan3_kernel<<<(NN + 255) / 256, 256, 0, stream>>>(scanned, partials, offsets, cursor);
    scatter_kernel<<<EE / 256, 256, 0, stream>>>(
        edge_index, edge_attr, cursor, srcs_p, dstd_p, ea_b);

    for (int l = 0; l < LL; l++) {
        const int ln = (l + 1 < LL) ? (l + 1) : l;   // next-layer attn/eps (dummy at last)
        edge_msg_kernel<<<EE / TEB, 256, 0, stream>>>(
            hbuf, ea_b, pi, pj, srcs_p, dstd_p, attn_b + l,
            edge_W + (size_t)l * EDD * DD, edge_b + (size_t)l * DD, z);
        mlp_mfma_kernel<<<NN / 64, 256, 0, stream>>>(
            z,
            w1t + (size_t)l * 32768, w2t + (size_t)l * 32768,
            b1 + (size_t)l * 2 * DD, bn1_g + (size_t)l * 2 * DD, bn1_b + (size_t)l * 2 * DD,
            b2 + (size_t)l * DD, bn_g + (size_t)l * DD, bn_b + (size_t)l * DD,
            attn_W + (size_t)ln * 2 * DD, eps + ln,
            (l == LL - 1) ? out : h, hbuf, pi, pj, z, (l < LL - 1) ? 1 : 0);
    }
}